// Round 7
// baseline (335.883 us; speedup 1.0000x reference)
//
#include <hip/hip_runtime.h>
#include <cstdint>
#include <cstddef>

#define B_   2
#define S_   21760
#define M_   (B_ * S_)     // 43520
#define D_   256
#define DFF_ 1024
#define EPS_ 1e-5f

typedef __attribute__((ext_vector_type(8))) short short8;
typedef __attribute__((ext_vector_type(4))) float f32x4;
typedef __attribute__((ext_vector_type(2))) float f32x2;

__device__ __forceinline__ ushort f2bf(float f) {
    uint x = __float_as_uint(f);
    return (ushort)((x + 0x7fffu + ((x >> 16) & 1u)) >> 16);
}
__device__ __forceinline__ float bf2f(ushort u) {
    return __uint_as_float(((uint)u) << 16);
}

// ---------------------------------------------------------------------------
// One-shot weight transpose+convert for ALL weights + off/attn bias concat.
// ---------------------------------------------------------------------------
__global__ __launch_bounds__(256) void wconv_all(
    const float* __restrict__ Wval, const float* __restrict__ Woff,
    const float* __restrict__ Wattn, const float* __restrict__ Wout,
    const float* __restrict__ Wff1, const float* __restrict__ Wff2,
    const float* __restrict__ boff, const float* __restrict__ battn,
    ushort* __restrict__ WT, float* __restrict__ bias_oa)
{
    const int i = blockIdx.x * 256 + threadIdx.x;
    if (i < 65536) {
        const int n = i >> 8, k = i & 255;
        WT[i] = f2bf(Wval[(size_t)k * 256 + n]);
    } else if (i < 163840) {
        const int j = i - 65536;
        const int n = j >> 8, k = j & 255;
        WT[i] = (n < 256) ? f2bf(Woff[(size_t)k * 256 + n])
                          : f2bf(Wattn[(size_t)k * 128 + (n - 256)]);
    } else if (i < 229376) {
        const int j = i - 163840;
        const int n = j >> 8, k = j & 255;
        WT[i] = f2bf(Wout[(size_t)k * 256 + n]);
    } else if (i < 491520) {
        const int j = i - 229376;
        const int n = j >> 8, k = j & 255;
        WT[i] = f2bf(Wff1[(size_t)k * 1024 + n]);
    } else if (i < 753664) {
        const int j = i - 491520;
        const int n = j >> 10, k = j & 1023;
        WT[i] = f2bf(Wff2[(size_t)k * 256 + n]);
    } else if (i < 753664 + 384) {
        const int j = i - 753664;
        bias_oa[j] = (j < 256) ? boff[j] : battn[j - 256];
    }
}

// ---------------------------------------------------------------------------
// src_bf = bf16(src); q_bf = bf16(src + pos)
// ---------------------------------------------------------------------------
__global__ __launch_bounds__(256) void cvt_pair(
    const float* __restrict__ src, const float* __restrict__ pos,
    ushort* __restrict__ sb, ushort* __restrict__ qb)
{
    const size_t i = ((size_t)blockIdx.x * 256 + threadIdx.x) * 4;
    if (i >= (size_t)M_ * 256) return;
    const float4 s = *(const float4*)(src + i);
    const float4 p = *(const float4*)(pos + i);
    ushort4 so, qo;
    so.x = f2bf(s.x); so.y = f2bf(s.y); so.z = f2bf(s.z); so.w = f2bf(s.w);
    qo.x = f2bf(s.x + p.x); qo.y = f2bf(s.y + p.y);
    qo.z = f2bf(s.z + p.z); qo.w = f2bf(s.w + p.w);
    *(ushort4*)(sb + i) = so;
    *(ushort4*)(qb + i) = qo;
}

// ---------------------------------------------------------------------------
// bf16 MFMA GEMM: 128x128 tile, BK=32, 4 waves, 4x4 16x16x32 fragments.
// mode 0: C row-major [M][N] bf16.   mode 2: C fp8 e4m3 head-major value.
// ---------------------------------------------------------------------------
__global__ __launch_bounds__(256) void mgemm(
    const ushort* __restrict__ A, const ushort* __restrict__ WT,
    const float* __restrict__ bias, ushort* __restrict__ C,
    int M, int N, int K, int relu, int mode)
{
    __shared__ __align__(16) ushort Als[128 * 32];
    __shared__ __align__(16) ushort Bls[128 * 32];

    const int tid = threadIdx.x;
    const int wv = tid >> 6, ln = tid & 63;
    const int m0 = blockIdx.y << 7, n0 = blockIdx.x << 7;
    const int wm = wv >> 1, wn = wv & 1;

    const int lrow = ln >> 2, lcol = (ln & 3) * 8;

    f32x4 acc[4][4];
    const f32x4 zz = {0.f, 0.f, 0.f, 0.f};
    #pragma unroll
    for (int i = 0; i < 4; i++)
        #pragma unroll
        for (int j = 0; j < 4; j++) acc[i][j] = zz;

    for (int k0 = 0; k0 < K; k0 += 32) {
        __syncthreads();
        #pragma unroll
        for (int r = 0; r < 2; ++r) {
            const int c = r * 4 + wv;
            const ushort* ga = A + (size_t)(m0 + c * 16 + lrow) * K + k0 + lcol;
            __builtin_amdgcn_global_load_lds(
                (const __attribute__((address_space(1))) uint*)ga,
                (__attribute__((address_space(3))) uint*)(Als + c * 512), 16, 0, 0);
            const ushort* gb = WT + (size_t)(n0 + c * 16 + lrow) * K + k0 + lcol;
            __builtin_amdgcn_global_load_lds(
                (const __attribute__((address_space(1))) uint*)gb,
                (__attribute__((address_space(3))) uint*)(Bls + c * 512), 16, 0, 0);
        }
        __syncthreads();

        const int fr = ln & 15, kb = (ln >> 4) * 8;
        short8 af[4], bfr[4];
        #pragma unroll
        for (int i = 0; i < 4; i++)
            af[i] = *(const short8*)&Als[(wm * 64 + i * 16 + fr) * 32 + kb];
        #pragma unroll
        for (int j = 0; j < 4; j++)
            bfr[j] = *(const short8*)&Bls[(wn * 64 + j * 16 + fr) * 32 + kb];
        #pragma unroll
        for (int i = 0; i < 4; i++)
            #pragma unroll
            for (int j = 0; j < 4; j++)
                acc[i][j] = __builtin_amdgcn_mfma_f32_16x16x32_bf16(
                    af[i], bfr[j], acc[i][j], 0, 0, 0);
    }

    uint8_t* C8 = (uint8_t*)C;
    const int fr = ln & 15, rq = (ln >> 4) * 4;
    #pragma unroll
    for (int j = 0; j < 4; j++) {
        const int col = n0 + wn * 64 + j * 16 + fr;
        const float bv = bias[col];
        #pragma unroll
        for (int i = 0; i < 4; i++) {
            #pragma unroll
            for (int r = 0; r < 4; r++) {
                const int row = m0 + wm * 64 + i * 16 + rq + r;
                float v = acc[i][j][r] + bv;
                if (relu) v = fmaxf(v, 0.f);
                if (mode == 0) {
                    C[(size_t)row * N + col] = f2bf(v);
                } else {
                    const int bb = (row >= S_) ? 1 : 0;
                    const int loc = row - bb * S_;
                    const int hh = col >> 5, ch = col & 31;
                    const int pk = __builtin_amdgcn_cvt_pk_fp8_f32(v, v, 0, false);
                    C8[((size_t)(bb * 8 + hh) * S_ + loc) * 32 + ch] = (uint8_t)(pk & 0xff);
                }
            }
        }
    }
}

// ---------------------------------------------------------------------------
// Fused GEMM (N=256, full row per block) + bias + residual + LayerNorm.
// BM=128, BN=256, BK=32, 512 threads = 8 waves (2 wm x 4 wn).
// out = LN(A@WT^T + bias + res) * g + be ; res is f32 (res32) or bf16 (res16);
// output f32 (o32) or bf16 (o16).
// ---------------------------------------------------------------------------
__global__ __launch_bounds__(512) void mgemm_ln(
    const ushort* __restrict__ A, const ushort* __restrict__ WT,
    const float* __restrict__ bias,
    const float* __restrict__ res32, const ushort* __restrict__ res16,
    const float* __restrict__ g, const float* __restrict__ be,
    float* __restrict__ o32, ushort* __restrict__ o16, int K)
{
    __shared__ __align__(16) ushort Als[128 * 32];
    __shared__ __align__(16) ushort Bls[256 * 32];
    __shared__ float red[4][128][2];
    __shared__ float stat[128][2];

    const int tid = threadIdx.x;
    const int wv = tid >> 6, ln = tid & 63;
    const int m0 = blockIdx.x << 7;
    const int wm = wv >> 2, wn = wv & 3;

    const int lrow = ln >> 2, lcol = (ln & 3) * 8;

    f32x4 acc[4][4];
    const f32x4 zz = {0.f, 0.f, 0.f, 0.f};
    #pragma unroll
    for (int i = 0; i < 4; i++)
        #pragma unroll
        for (int j = 0; j < 4; j++) acc[i][j] = zz;

    for (int k0 = 0; k0 < K; k0 += 32) {
        __syncthreads();
        // A: wave wv stages rows [wv*16, wv*16+16)
        {
            const ushort* ga = A + (size_t)(m0 + wv * 16 + lrow) * K + k0 + lcol;
            __builtin_amdgcn_global_load_lds(
                (const __attribute__((address_space(1))) uint*)ga,
                (__attribute__((address_space(3))) uint*)(Als + wv * 512), 16, 0, 0);
        }
        // B: wave wv stages rows [wv*32, wv*32+32) as two 16-row chunks
        #pragma unroll
        for (int r = 0; r < 2; ++r) {
            const int c = wv * 2 + r;
            const ushort* gb = WT + (size_t)(c * 16 + lrow) * K + k0 + lcol;
            __builtin_amdgcn_global_load_lds(
                (const __attribute__((address_space(1))) uint*)gb,
                (__attribute__((address_space(3))) uint*)(Bls + c * 512), 16, 0, 0);
        }
        __syncthreads();

        const int fr = ln & 15, kb = (ln >> 4) * 8;
        short8 af[4], bfr[4];
        #pragma unroll
        for (int i = 0; i < 4; i++)
            af[i] = *(const short8*)&Als[(wm * 64 + i * 16 + fr) * 32 + kb];
        #pragma unroll
        for (int j = 0; j < 4; j++)
            bfr[j] = *(const short8*)&Bls[(wn * 64 + j * 16 + fr) * 32 + kb];
        #pragma unroll
        for (int i = 0; i < 4; i++)
            #pragma unroll
            for (int j = 0; j < 4; j++)
                acc[i][j] = __builtin_amdgcn_mfma_f32_16x16x32_bf16(
                    af[i], bfr[j], acc[i][j], 0, 0, 0);
    }

    const int fr = ln & 15, rq = (ln >> 4) * 4;

    // bias per j-column (uniform over i,r)
    float bj[4], gj[4], bej[4];
    #pragma unroll
    for (int j = 0; j < 4; j++) {
        const int col = wn * 64 + j * 16 + fr;
        bj[j] = bias[col];
        gj[j] = g[col];
        bej[j] = be[col];
    }

    // v = acc + bias + residual; per-(i,r)-row partial sums over this lane's 4 cols
    float rs[4][4], rq2[4][4];
    #pragma unroll
    for (int i = 0; i < 4; i++) {
        #pragma unroll
        for (int r = 0; r < 4; r++) {
            const int row = m0 + wm * 64 + i * 16 + rq + r;
            float s = 0.f, s2 = 0.f;
            #pragma unroll
            for (int j = 0; j < 4; j++) {
                const int col = wn * 64 + j * 16 + fr;
                const size_t ofs = (size_t)row * 256 + col;
                const float rv = res32 ? res32[ofs] : bf2f(res16[ofs]);
                float v = acc[i][j][r] + bj[j] + rv;
                acc[i][j][r] = v;
                s += v;
                s2 += v * v;
            }
            rs[i][r] = s;
            rq2[i][r] = s2;
        }
    }

    // butterfly over the 16 fr-lanes (share the same rows)
    #pragma unroll
    for (int d = 1; d < 16; d <<= 1) {
        #pragma unroll
        for (int i = 0; i < 4; i++)
            #pragma unroll
            for (int r = 0; r < 4; r++) {
                rs[i][r]  += __shfl_xor(rs[i][r], d);
                rq2[i][r] += __shfl_xor(rq2[i][r], d);
            }
    }

    // lane fr==0 of each rq-group writes partials: red[wn][localrow][{0,1}]
    if (fr == 0) {
        #pragma unroll
        for (int i = 0; i < 4; i++)
            #pragma unroll
            for (int r = 0; r < 4; r++) {
                const int lr = wm * 64 + i * 16 + rq + r;
                red[wn][lr][0] = rs[i][r];
                red[wn][lr][1] = rq2[i][r];
            }
    }
    __syncthreads();

    if (tid < 128) {
        float s = red[0][tid][0] + red[1][tid][0] + red[2][tid][0] + red[3][tid][0];
        float s2 = red[0][tid][1] + red[1][tid][1] + red[2][tid][1] + red[3][tid][1];
        const float mean = s * (1.f / 256.f);
        const float var = s2 * (1.f / 256.f) - mean * mean;
        stat[tid][0] = mean;
        stat[tid][1] = rsqrtf(var + EPS_);
    }
    __syncthreads();

    #pragma unroll
    for (int i = 0; i < 4; i++) {
        #pragma unroll
        for (int r = 0; r < 4; r++) {
            const int lr = wm * 64 + i * 16 + rq + r;
            const int row = m0 + lr;
            const float mean = stat[lr][0], rstd = stat[lr][1];
            #pragma unroll
            for (int j = 0; j < 4; j++) {
                const int col = wn * 64 + j * 16 + fr;
                const float o = (acc[i][j][r] - mean) * rstd * gj[j] + bej[j];
                if (o32) o32[(size_t)row * 256 + col] = o;
                else     o16[(size_t)row * 256 + col] = f2bf(o);
            }
        }
    }
}

// ---------------------------------------------------------------------------
// Deformable sampling v6: cooperative corner-PAIR (64B region) loads.
// ---------------------------------------------------------------------------
__global__ __launch_bounds__(256) void sample6(
    const uint8_t* __restrict__ value, const ushort* __restrict__ offaw,
    const float* __restrict__ refp, ushort* __restrict__ samp)
{
    const int nwg = M_ / 8;                       // 5440 (%8 == 0)
    const int bid = blockIdx.x;
    const int wg = (bid & 7) * (nwg >> 3) + (bid >> 3);

    const int t = threadIdx.x;
    const int q = wg * 8 + (t >> 5);
    const int w = t & 31;
    const int h = w >> 2, cg = w & 3;
    const int half = cg >> 1;
    const int b = q / S_;

    const ushort* awq = offaw + (size_t)q * 384 + 256 + h * 16;
    const uint4 la = *(const uint4*)awq;
    const uint4 lb = *(const uint4*)(awq + 8);
    const uint lgu[8] = {la.x, la.y, la.z, la.w, lb.x, lb.y, lb.z, lb.w};
    float aj[16];
    float mx = -1e30f;
    #pragma unroll
    for (int k = 0; k < 8; k++) {
        aj[2 * k]     = bf2f((ushort)(lgu[k] & 0xffff));
        aj[2 * k + 1] = bf2f((ushort)(lgu[k] >> 16));
        mx = fmaxf(mx, fmaxf(aj[2 * k], aj[2 * k + 1]));
    }
    float sum = 0.f;
    #pragma unroll
    for (int s = 0; s < 16; s++) { aj[s] = __expf(aj[s] - mx); sum += aj[s]; }
    const float inv = 1.f / sum;
    #pragma unroll
    for (int s = 0; s < 16; s++) aj[s] *= inv;

    const ushort* ofq = offaw + (size_t)q * 384 + h * 32;
    const uint4 o0 = *(const uint4*)ofq;
    const uint4 o1 = *(const uint4*)(ofq + 8);
    const uint4 o2 = *(const uint4*)(ofq + 16);
    const uint4 o3 = *(const uint4*)(ofq + 24);
    const uint ou[16] = {o0.x, o0.y, o0.z, o0.w, o1.x, o1.y, o1.z, o1.w,
                         o2.x, o2.y, o2.z, o2.w, o3.x, o3.y, o3.z, o3.w};
    const float* rp = refp + (size_t)q * 8;
    const float4 rpa = *(const float4*)rp;
    const float4 rpb = *(const float4*)(rp + 4);
    const float rxa[4] = {rpa.x, rpa.z, rpb.x, rpb.z};
    const float rya[4] = {rpa.y, rpa.w, rpb.y, rpb.w};
    const int   stv[4] = {0, 16384, 20480, 21504};

    const uint8_t* vb = value + (size_t)(b * 8 + h) * S_ * 32 + cg * 16;

    f32x2 acc[8];
    #pragma unroll
    for (int k = 0; k < 8; k++) acc[k] = (f32x2){0.f, 0.f};

    #pragma unroll
    for (int l = 0; l < 4; l++) {
        const int Wl = 128 >> l;
        const float fW = (float)Wl;
        const int st = stv[l];
        const float rx = rxa[l], ry = rya[l];

        float rw[8];
        int   rix[8];
        #pragma unroll
        for (int j = 0; j < 4; j++) {
            const int s = l * 4 + j;
            const float ox = bf2f((ushort)(ou[s] & 0xffff));
            const float oy = bf2f((ushort)(ou[s] >> 16));
            const float x = fmaf(rx, fW, ox) - 0.5f;
            const float y = fmaf(ry, fW, oy) - 0.5f;
            const float fx0 = floorf(x), fy0 = floorf(y);
            const float dx = x - fx0, dy = y - fy0;
            const int x0 = (int)fx0, y0 = (int)fy0;

            const int bx = min(max(x0, 0), Wl - 2);
            const float mwx0 = ((x0 >= 0) & (x0 < Wl)) ? (1.f - dx) : 0.f;
            const float mwx1 = ((x0 + 1 >= 0) & (x0 + 1 < Wl)) ? dx : 0.f;
            const int xc0 = min(max(x0, 0), Wl - 1);
            const int xc1 = min(max(x0 + 1, 0), Wl - 1);
            const float wAx = (xc0 == bx ? mwx0 : 0.f) + (xc1 == bx ? mwx1 : 0.f);
            const float wBx = (xc0 == bx + 1 ? mwx0 : 0.f) + (xc1 == bx + 1 ? mwx1 : 0.f);
            const float wsel = half ? wBx : wAx;

            const int yc0 = min(max(y0, 0), Wl - 1);
            const int yc1 = min(max(y0 + 1, 0), Wl - 1);
            const float mwy0 = ((y0 >= 0) & (y0 < Wl)) ? (1.f - dy) : 0.f;
            const float mwy1 = ((y0 + 1 >= 0) & (y0 + 1 < Wl)) ? dy : 0.f;

            const float aw = aj[s] * wsel;
            rw[2 * j]      = aw * mwy0;
            rix[2 * j]     = (st + yc0 * Wl + bx) * 32;
            rw[2 * j + 1]  = aw * mwy1;
            rix[2 * j + 1] = (st + yc1 * Wl + bx) * 32;
        }

        #pragma unroll
        for (int r = 0; r < 8; r++) {
            const uint4 u = *(const uint4*)(vb + rix[r]);
            const f32x2 w2 = {rw[r], rw[r]};
            acc[0] += w2 * __builtin_amdgcn_cvt_pk_f32_fp8((int)u.x, false);
            acc[1] += w2 * __builtin_amdgcn_cvt_pk_f32_fp8((int)u.x, true);
            acc[2] += w2 * __builtin_amdgcn_cvt_pk_f32_fp8((int)u.y, false);
            acc[3] += w2 * __builtin_amdgcn_cvt_pk_f32_fp8((int)u.y, true);
            acc[4] += w2 * __builtin_amdgcn_cvt_pk_f32_fp8((int)u.z, false);
            acc[5] += w2 * __builtin_amdgcn_cvt_pk_f32_fp8((int)u.z, true);
            acc[6] += w2 * __builtin_amdgcn_cvt_pk_f32_fp8((int)u.w, false);
            acc[7] += w2 * __builtin_amdgcn_cvt_pk_f32_fp8((int)u.w, true);
        }
    }

    #pragma unroll
    for (int k = 0; k < 8; k++) {
        acc[k].x += __shfl_xor(acc[k].x, 2);
        acc[k].y += __shfl_xor(acc[k].y, 2);
    }

    f32x2 r0, r1, r2, r3;
    if (half == 0) { r0 = acc[0]; r1 = acc[1]; r2 = acc[2]; r3 = acc[3]; }
    else           { r0 = acc[4]; r1 = acc[5]; r2 = acc[6]; r3 = acc[7]; }

    const int ch_start = (cg & 1) * 16 + half * 8;
    uint4 o;
    o.x = (uint)f2bf(r0.x) | ((uint)f2bf(r0.y) << 16);
    o.y = (uint)f2bf(r1.x) | ((uint)f2bf(r1.y) << 16);
    o.z = (uint)f2bf(r2.x) | ((uint)f2bf(r2.y) << 16);
    o.w = (uint)f2bf(r3.x) | ((uint)f2bf(r3.y) << 16);
    *(uint4*)(samp + (size_t)q * 256 + h * 32 + ch_start) = o;
}

// ---------------------------------------------------------------------------
extern "C" void kernel_launch(void* const* d_in, const int* in_sizes, int n_in,
                              void* d_out, int out_size, void* d_ws, size_t ws_size,
                              hipStream_t stream)
{
    const float* src    = (const float*)d_in[0];
    const float* pos    = (const float*)d_in[1];
    const float* refp   = (const float*)d_in[2];
    const float* W_off  = (const float*)d_in[5];
    const float* b_off  = (const float*)d_in[6];
    const float* W_attn = (const float*)d_in[7];
    const float* b_attn = (const float*)d_in[8];
    const float* W_val  = (const float*)d_in[9];
    const float* b_val  = (const float*)d_in[10];
    const float* W_out  = (const float*)d_in[11];
    const float* b_out  = (const float*)d_in[12];
    const float* g1     = (const float*)d_in[13];
    const float* be1    = (const float*)d_in[14];
    const float* W_ff1  = (const float*)d_in[15];
    const float* b_ff1  = (const float*)d_in[16];
    const float* W_ff2  = (const float*)d_in[17];
    const float* b_ff2  = (const float*)d_in[18];
    const float* g2     = (const float*)d_in[19];
    const float* be2    = (const float*)d_in[20];
    float* out = (float*)d_out;

    const size_t szMDh = (size_t)M_ * 256 * 2;      // 22,282,240 B
    const size_t szOAh = (size_t)M_ * 384 * 2;      // 33,423,360 B

    char* ws = (char*)d_ws;
    ushort* WT      = (ushort*)ws;
    ushort* WT_val  = WT;
    ushort* WT_oa   = WT + 65536;
    ushort* WT_out  = WT + 163840;
    ushort* WT_ff1  = WT + 229376;
    ushort* WT_ff2  = WT + 491520;
    float*  bias_oa = (float*)(ws + 1507328);

    const size_t o_src  = 2097152;                  // src_bf  -> samp, hbuf
    const size_t o_q    = o_src + szMDh;            // q_bf
    const size_t o_val  = o_q   + szMDh;            // value (fp8 head-major)
    const size_t o_oa   = o_val + szMDh;            // offaw [M][384]
    const size_t o_x    = o_oa  + szOAh;            // x_bf
    const size_t o_ffn  = o_x   + szMDh;            // (spare)

    ushort* src_bf = (ushort*)(ws + o_src);
    ushort* q_bf   = (ushort*)(ws + o_q);
    ushort* val_f8 = (ushort*)(ws + o_val);
    ushort* offaw  = (ushort*)(ws + o_oa);
    ushort* x_bf   = (ushort*)(ws + o_x);
    ushort* samp_bf = src_bf;   // src_bf dead after value GEMM
    ushort* hbuf    = q_bf;     // q_bf dead after offaw GEMM; spans q+val+offaw
                                // = szMDh*2 + szOAh = 78 MB < needed 89 MB? NO:
    // hbuf needs M*1024*2 = 89.1 MB. q+val+oa = 22.3+22.3+33.4 = 78 MB. Short.
    // Use src_bf start instead (samp dead after attn GEMM... but attn GEMM
    // reads samp as A!). ff1 runs AFTER attn GEMM, so src..oa = 100.3 MB: OK.
    hbuf = src_bf;

    // 0) all weight converts + bias concat
    wconv_all<<<(753664 + 384 + 255) / 256, 256, 0, stream>>>(
        W_val, W_off, W_attn, W_out, W_ff1, W_ff2, b_off, b_attn, WT, bias_oa);
    // 1) activation converts
    cvt_pair<<<(M_ * 256 / 4 + 255) / 256, 256, 0, stream>>>(src, pos, src_bf, q_bf);
    // 2) value = src @ W_val + b_val  (fp8 head-major output)
    mgemm<<<dim3(2, M_ / 128), 256, 0, stream>>>(src_bf, WT_val, b_val, val_f8, M_, 256, 256, 0, 2);
    // 3) offaw = (src+pos) @ [W_off|W_attn] + [b_off|b_attn]
    mgemm<<<dim3(3, M_ / 128), 256, 0, stream>>>(q_bf, WT_oa, bias_oa, offaw, M_, 384, 256, 0, 0);
    // 4) sampling
    sample6<<<M_ / 8, 256, 0, stream>>>((const uint8_t*)val_f8, offaw, refp, samp_bf);
    // 5) x = LN(src + samp @ W_out + b_out)   [fused GEMM+residual+LN]
    mgemm_ln<<<M_ / 128, 512, 0, stream>>>(samp_bf, WT_out, b_out,
                                           src, nullptr, g1, be1,
                                           nullptr, x_bf, 256);
    // 6) FFN1: h = relu(x @ W_ff1 + b_ff1)
    mgemm<<<dim3(8, M_ / 128), 256, 0, stream>>>(x_bf, WT_ff1, b_ff1, hbuf, M_, DFF_, 256, 1, 0);
    // 7) out = LN(x + h @ W_ff2 + b_ff2)      [fused GEMM+residual+LN]
    mgemm_ln<<<M_ / 128, 512, 0, stream>>>(hbuf, WT_ff2, b_ff2,
                                           nullptr, x_bf, g2, be2,
                                           out, nullptr, DFF_);
}

// Round 8
// 316.599 us; speedup vs baseline: 1.0609x; 1.0609x over previous
//
#include <hip/hip_runtime.h>
#include <cstdint>
#include <cstddef>

#define B_   2
#define S_   21760
#define M_   (B_ * S_)     // 43520
#define D_   256
#define DFF_ 1024
#define EPS_ 1e-5f

typedef __attribute__((ext_vector_type(8))) short short8;
typedef __attribute__((ext_vector_type(4))) float f32x4;
typedef __attribute__((ext_vector_type(2))) float f32x2;

__device__ __forceinline__ ushort f2bf(float f) {
    uint x = __float_as_uint(f);
    return (ushort)((x + 0x7fffu + ((x >> 16) & 1u)) >> 16);
}
__device__ __forceinline__ float bf2f(ushort u) {
    return __uint_as_float(((uint)u) << 16);
}

// ---------------------------------------------------------------------------
// One-shot weight transpose+convert for ALL weights + off/attn bias concat.
// ---------------------------------------------------------------------------
__global__ __launch_bounds__(256) void wconv_all(
    const float* __restrict__ Wval, const float* __restrict__ Woff,
    const float* __restrict__ Wattn, const float* __restrict__ Wout,
    const float* __restrict__ Wff1, const float* __restrict__ Wff2,
    const float* __restrict__ boff, const float* __restrict__ battn,
    ushort* __restrict__ WT, float* __restrict__ bias_oa)
{
    const int i = blockIdx.x * 256 + threadIdx.x;
    if (i < 65536) {
        const int n = i >> 8, k = i & 255;
        WT[i] = f2bf(Wval[(size_t)k * 256 + n]);
    } else if (i < 163840) {
        const int j = i - 65536;
        const int n = j >> 8, k = j & 255;
        WT[i] = (n < 256) ? f2bf(Woff[(size_t)k * 256 + n])
                          : f2bf(Wattn[(size_t)k * 128 + (n - 256)]);
    } else if (i < 229376) {
        const int j = i - 163840;
        const int n = j >> 8, k = j & 255;
        WT[i] = f2bf(Wout[(size_t)k * 256 + n]);
    } else if (i < 491520) {
        const int j = i - 229376;
        const int n = j >> 8, k = j & 255;
        WT[i] = f2bf(Wff1[(size_t)k * 1024 + n]);
    } else if (i < 753664) {
        const int j = i - 491520;
        const int n = j >> 10, k = j & 1023;
        WT[i] = f2bf(Wff2[(size_t)k * 256 + n]);
    } else if (i < 753664 + 384) {
        const int j = i - 753664;
        bias_oa[j] = (j < 256) ? boff[j] : battn[j - 256];
    }
}

// ---------------------------------------------------------------------------
// src_bf = bf16(src); q_bf = bf16(src + pos)
// ---------------------------------------------------------------------------
__global__ __launch_bounds__(256) void cvt_pair(
    const float* __restrict__ src, const float* __restrict__ pos,
    ushort* __restrict__ sb, ushort* __restrict__ qb)
{
    const size_t i = ((size_t)blockIdx.x * 256 + threadIdx.x) * 4;
    if (i >= (size_t)M_ * 256) return;
    const float4 s = *(const float4*)(src + i);
    const float4 p = *(const float4*)(pos + i);
    ushort4 so, qo;
    so.x = f2bf(s.x); so.y = f2bf(s.y); so.z = f2bf(s.z); so.w = f2bf(s.w);
    qo.x = f2bf(s.x + p.x); qo.y = f2bf(s.y + p.y);
    qo.z = f2bf(s.z + p.z); qo.w = f2bf(s.w + p.w);
    *(ushort4*)(sb + i) = so;
    *(ushort4*)(qb + i) = qo;
}

// ---------------------------------------------------------------------------
// bf16 MFMA GEMM: 128x128 tile, BK=32, 4 waves, 4x4 16x16x32 fragments.
// mode 0: C row-major [M][N] bf16.   mode 2: C fp8 e4m3 head-major value.
// ---------------------------------------------------------------------------
__global__ __launch_bounds__(256) void mgemm(
    const ushort* __restrict__ A, const ushort* __restrict__ WT,
    const float* __restrict__ bias, ushort* __restrict__ C,
    int M, int N, int K, int relu, int mode)
{
    __shared__ __align__(16) ushort Als[128 * 32];
    __shared__ __align__(16) ushort Bls[128 * 32];

    const int tid = threadIdx.x;
    const int wv = tid >> 6, ln = tid & 63;
    const int m0 = blockIdx.y << 7, n0 = blockIdx.x << 7;
    const int wm = wv >> 1, wn = wv & 1;

    const int lrow = ln >> 2, lcol = (ln & 3) * 8;

    f32x4 acc[4][4];
    const f32x4 zz = {0.f, 0.f, 0.f, 0.f};
    #pragma unroll
    for (int i = 0; i < 4; i++)
        #pragma unroll
        for (int j = 0; j < 4; j++) acc[i][j] = zz;

    for (int k0 = 0; k0 < K; k0 += 32) {
        __syncthreads();
        #pragma unroll
        for (int r = 0; r < 2; ++r) {
            const int c = r * 4 + wv;
            const ushort* ga = A + (size_t)(m0 + c * 16 + lrow) * K + k0 + lcol;
            __builtin_amdgcn_global_load_lds(
                (const __attribute__((address_space(1))) uint*)ga,
                (__attribute__((address_space(3))) uint*)(Als + c * 512), 16, 0, 0);
            const ushort* gb = WT + (size_t)(n0 + c * 16 + lrow) * K + k0 + lcol;
            __builtin_amdgcn_global_load_lds(
                (const __attribute__((address_space(1))) uint*)gb,
                (__attribute__((address_space(3))) uint*)(Bls + c * 512), 16, 0, 0);
        }
        __syncthreads();

        const int fr = ln & 15, kb = (ln >> 4) * 8;
        short8 af[4], bfr[4];
        #pragma unroll
        for (int i = 0; i < 4; i++)
            af[i] = *(const short8*)&Als[(wm * 64 + i * 16 + fr) * 32 + kb];
        #pragma unroll
        for (int j = 0; j < 4; j++)
            bfr[j] = *(const short8*)&Bls[(wn * 64 + j * 16 + fr) * 32 + kb];
        #pragma unroll
        for (int i = 0; i < 4; i++)
            #pragma unroll
            for (int j = 0; j < 4; j++)
                acc[i][j] = __builtin_amdgcn_mfma_f32_16x16x32_bf16(
                    af[i], bfr[j], acc[i][j], 0, 0, 0);
    }

    uint8_t* C8 = (uint8_t*)C;
    const int fr = ln & 15, rq = (ln >> 4) * 4;
    #pragma unroll
    for (int j = 0; j < 4; j++) {
        const int col = n0 + wn * 64 + j * 16 + fr;
        const float bv = bias[col];
        #pragma unroll
        for (int i = 0; i < 4; i++) {
            #pragma unroll
            for (int r = 0; r < 4; r++) {
                const int row = m0 + wm * 64 + i * 16 + rq + r;
                float v = acc[i][j][r] + bv;
                if (relu) v = fmaxf(v, 0.f);
                if (mode == 0) {
                    C[(size_t)row * N + col] = f2bf(v);
                } else {
                    const int bb = (row >= S_) ? 1 : 0;
                    const int loc = row - bb * S_;
                    const int hh = col >> 5, ch = col & 31;
                    const int pk = __builtin_amdgcn_cvt_pk_fp8_f32(v, v, 0, false);
                    C8[((size_t)(bb * 8 + hh) * S_ + loc) * 32 + ch] = (uint8_t)(pk & 0xff);
                }
            }
        }
    }
}

// ---------------------------------------------------------------------------
// Fused GEMM (full 256-wide row per block) + bias + residual + LayerNorm.
// v2: BM=64, BN=256, BK=32, 256 threads = 4 waves (wave wn owns 64 cols),
// grid = M/64 = 680 blocks, double-buffered LDS, 2-phase pipeline:
// per K-step {issue next-tile global_load_lds -> ds_read cur -> MFMA -> bar}.
// out = LN(A@WT^T + bias + res) * g + be
// ---------------------------------------------------------------------------
__global__ __launch_bounds__(256) void mgemm_ln(
    const ushort* __restrict__ A, const ushort* __restrict__ WT,
    const float* __restrict__ bias,
    const float* __restrict__ res32, const ushort* __restrict__ res16,
    const float* __restrict__ g, const float* __restrict__ be,
    float* __restrict__ o32, ushort* __restrict__ o16, int K)
{
    __shared__ __align__(16) ushort Als[2][64 * 32];
    __shared__ __align__(16) ushort Bls[2][256 * 32];
    __shared__ float red[4][64][2];
    __shared__ float stat[64][2];

    const int tid = threadIdx.x;
    const int wv = tid >> 6, ln = tid & 63;
    const int m0 = blockIdx.x << 6;
    const int wn = wv;                       // this wave's 64-col span

    const int lrow = ln >> 2, lcol = (ln & 3) * 8;
    const int fr = ln & 15, kb = (ln >> 4) * 8, rq = (ln >> 4) * 4;

    f32x4 acc[4][4];
    const f32x4 zz = {0.f, 0.f, 0.f, 0.f};
    #pragma unroll
    for (int i = 0; i < 4; i++)
        #pragma unroll
        for (int j = 0; j < 4; j++) acc[i][j] = zz;

    const int NT = K >> 5;

    // prologue: stage tile 0 into buffer 0
    {
        const ushort* ga = A + (size_t)(m0 + wv * 16 + lrow) * K + lcol;
        __builtin_amdgcn_global_load_lds(
            (const __attribute__((address_space(1))) uint*)ga,
            (__attribute__((address_space(3))) uint*)(&Als[0][wv * 512]), 16, 0, 0);
        #pragma unroll
        for (int r = 0; r < 4; ++r) {
            const int c = r * 4 + wv;
            const ushort* gb = WT + (size_t)(c * 16 + lrow) * K + lcol;
            __builtin_amdgcn_global_load_lds(
                (const __attribute__((address_space(1))) uint*)gb,
                (__attribute__((address_space(3))) uint*)(&Bls[0][c * 512]), 16, 0, 0);
        }
    }
    __syncthreads();   // drains vmcnt(0) before barrier (compiler-inserted)

    int cur = 0;
    for (int t = 0; t < NT; t++) {
        // issue next-tile staging into the other buffer (overlaps with MFMA)
        if (t + 1 < NT) {
            const int k0 = (t + 1) << 5;
            const ushort* ga = A + (size_t)(m0 + wv * 16 + lrow) * K + k0 + lcol;
            __builtin_amdgcn_global_load_lds(
                (const __attribute__((address_space(1))) uint*)ga,
                (__attribute__((address_space(3))) uint*)(&Als[cur ^ 1][wv * 512]), 16, 0, 0);
            #pragma unroll
            for (int r = 0; r < 4; ++r) {
                const int c = r * 4 + wv;
                const ushort* gb = WT + (size_t)(c * 16 + lrow) * K + k0 + lcol;
                __builtin_amdgcn_global_load_lds(
                    (const __attribute__((address_space(1))) uint*)gb,
                    (__attribute__((address_space(3))) uint*)(&Bls[cur ^ 1][c * 512]), 16, 0, 0);
            }
        }

        // compute current tile
        short8 af[4], bfr[4];
        #pragma unroll
        for (int i = 0; i < 4; i++)
            af[i] = *(const short8*)&Als[cur][(i * 16 + fr) * 32 + kb];
        #pragma unroll
        for (int j = 0; j < 4; j++)
            bfr[j] = *(const short8*)&Bls[cur][(wn * 64 + j * 16 + fr) * 32 + kb];
        #pragma unroll
        for (int i = 0; i < 4; i++)
            #pragma unroll
            for (int j = 0; j < 4; j++)
                acc[i][j] = __builtin_amdgcn_mfma_f32_16x16x32_bf16(
                    af[i], bfr[j], acc[i][j], 0, 0, 0);

        __syncthreads();   // waits next-tile loads (vmcnt0) + all reads retired
        cur ^= 1;
    }

    // ---- epilogue: bias + residual + LayerNorm, all in-register/LDS
    float bj[4], gj[4], bej[4];
    #pragma unroll
    for (int j = 0; j < 4; j++) {
        const int col = wn * 64 + j * 16 + fr;
        bj[j] = bias[col];
        gj[j] = g[col];
        bej[j] = be[col];
    }

    float rs[4][4], rq2[4][4];
    #pragma unroll
    for (int i = 0; i < 4; i++) {
        #pragma unroll
        for (int r = 0; r < 4; r++) {
            const int row = m0 + i * 16 + rq + r;
            float s = 0.f, s2 = 0.f;
            #pragma unroll
            for (int j = 0; j < 4; j++) {
                const int col = wn * 64 + j * 16 + fr;
                const size_t ofs = (size_t)row * 256 + col;
                const float rv = res32 ? res32[ofs] : bf2f(res16[ofs]);
                float v = acc[i][j][r] + bj[j] + rv;
                acc[i][j][r] = v;
                s += v;
                s2 += v * v;
            }
            rs[i][r] = s;
            rq2[i][r] = s2;
        }
    }

    #pragma unroll
    for (int d = 1; d < 16; d <<= 1) {
        #pragma unroll
        for (int i = 0; i < 4; i++)
            #pragma unroll
            for (int r = 0; r < 4; r++) {
                rs[i][r]  += __shfl_xor(rs[i][r], d);
                rq2[i][r] += __shfl_xor(rq2[i][r], d);
            }
    }

    if (fr == 0) {
        #pragma unroll
        for (int i = 0; i < 4; i++)
            #pragma unroll
            for (int r = 0; r < 4; r++) {
                const int lr = i * 16 + rq + r;
                red[wn][lr][0] = rs[i][r];
                red[wn][lr][1] = rq2[i][r];
            }
    }
    __syncthreads();

    if (tid < 64) {
        float s  = red[0][tid][0] + red[1][tid][0] + red[2][tid][0] + red[3][tid][0];
        float s2 = red[0][tid][1] + red[1][tid][1] + red[2][tid][1] + red[3][tid][1];
        const float mean = s * (1.f / 256.f);
        const float var = s2 * (1.f / 256.f) - mean * mean;
        stat[tid][0] = mean;
        stat[tid][1] = rsqrtf(var + EPS_);
    }
    __syncthreads();

    #pragma unroll
    for (int i = 0; i < 4; i++) {
        #pragma unroll
        for (int r = 0; r < 4; r++) {
            const int lr = i * 16 + rq + r;
            const int row = m0 + lr;
            const float mean = stat[lr][0], rstd = stat[lr][1];
            #pragma unroll
            for (int j = 0; j < 4; j++) {
                const int col = wn * 64 + j * 16 + fr;
                const float o = (acc[i][j][r] - mean) * rstd * gj[j] + bej[j];
                if (o32) o32[(size_t)row * 256 + col] = o;
                else     o16[(size_t)row * 256 + col] = f2bf(o);
            }
        }
    }
}

// ---------------------------------------------------------------------------
// Deformable sampling v6: cooperative corner-PAIR (64B region) loads.
// ---------------------------------------------------------------------------
__global__ __launch_bounds__(256) void sample6(
    const uint8_t* __restrict__ value, const ushort* __restrict__ offaw,
    const float* __restrict__ refp, ushort* __restrict__ samp)
{
    const int nwg = M_ / 8;                       // 5440 (%8 == 0)
    const int bid = blockIdx.x;
    const int wg = (bid & 7) * (nwg >> 3) + (bid >> 3);

    const int t = threadIdx.x;
    const int q = wg * 8 + (t >> 5);
    const int w = t & 31;
    const int h = w >> 2, cg = w & 3;
    const int half = cg >> 1;
    const int b = q / S_;

    const ushort* awq = offaw + (size_t)q * 384 + 256 + h * 16;
    const uint4 la = *(const uint4*)awq;
    const uint4 lb = *(const uint4*)(awq + 8);
    const uint lgu[8] = {la.x, la.y, la.z, la.w, lb.x, lb.y, lb.z, lb.w};
    float aj[16];
    float mx = -1e30f;
    #pragma unroll
    for (int k = 0; k < 8; k++) {
        aj[2 * k]     = bf2f((ushort)(lgu[k] & 0xffff));
        aj[2 * k + 1] = bf2f((ushort)(lgu[k] >> 16));
        mx = fmaxf(mx, fmaxf(aj[2 * k], aj[2 * k + 1]));
    }
    float sum = 0.f;
    #pragma unroll
    for (int s = 0; s < 16; s++) { aj[s] = __expf(aj[s] - mx); sum += aj[s]; }
    const float inv = 1.f / sum;
    #pragma unroll
    for (int s = 0; s < 16; s++) aj[s] *= inv;

    const ushort* ofq = offaw + (size_t)q * 384 + h * 32;
    const uint4 o0 = *(const uint4*)ofq;
    const uint4 o1 = *(const uint4*)(ofq + 8);
    const uint4 o2 = *(const uint4*)(ofq + 16);
    const uint4 o3 = *(const uint4*)(ofq + 24);
    const uint ou[16] = {o0.x, o0.y, o0.z, o0.w, o1.x, o1.y, o1.z, o1.w,
                         o2.x, o2.y, o2.z, o2.w, o3.x, o3.y, o3.z, o3.w};
    const float* rp = refp + (size_t)q * 8;
    const float4 rpa = *(const float4*)rp;
    const float4 rpb = *(const float4*)(rp + 4);
    const float rxa[4] = {rpa.x, rpa.z, rpb.x, rpb.z};
    const float rya[4] = {rpa.y, rpa.w, rpb.y, rpb.w};
    const int   stv[4] = {0, 16384, 20480, 21504};

    const uint8_t* vb = value + (size_t)(b * 8 + h) * S_ * 32 + cg * 16;

    f32x2 acc[8];
    #pragma unroll
    for (int k = 0; k < 8; k++) acc[k] = (f32x2){0.f, 0.f};

    #pragma unroll
    for (int l = 0; l < 4; l++) {
        const int Wl = 128 >> l;
        const float fW = (float)Wl;
        const int st = stv[l];
        const float rx = rxa[l], ry = rya[l];

        float rw[8];
        int   rix[8];
        #pragma unroll
        for (int j = 0; j < 4; j++) {
            const int s = l * 4 + j;
            const float ox = bf2f((ushort)(ou[s] & 0xffff));
            const float oy = bf2f((ushort)(ou[s] >> 16));
            const float x = fmaf(rx, fW, ox) - 0.5f;
            const float y = fmaf(ry, fW, oy) - 0.5f;
            const float fx0 = floorf(x), fy0 = floorf(y);
            const float dx = x - fx0, dy = y - fy0;
            const int x0 = (int)fx0, y0 = (int)fy0;

            const int bx = min(max(x0, 0), Wl - 2);
            const float mwx0 = ((x0 >= 0) & (x0 < Wl)) ? (1.f - dx) : 0.f;
            const float mwx1 = ((x0 + 1 >= 0) & (x0 + 1 < Wl)) ? dx : 0.f;
            const int xc0 = min(max(x0, 0), Wl - 1);
            const int xc1 = min(max(x0 + 1, 0), Wl - 1);
            const float wAx = (xc0 == bx ? mwx0 : 0.f) + (xc1 == bx ? mwx1 : 0.f);
            const float wBx = (xc0 == bx + 1 ? mwx0 : 0.f) + (xc1 == bx + 1 ? mwx1 : 0.f);
            const float wsel = half ? wBx : wAx;

            const int yc0 = min(max(y0, 0), Wl - 1);
            const int yc1 = min(max(y0 + 1, 0), Wl - 1);
            const float mwy0 = ((y0 >= 0) & (y0 < Wl)) ? (1.f - dy) : 0.f;
            const float mwy1 = ((y0 + 1 >= 0) & (y0 + 1 < Wl)) ? dy : 0.f;

            const float aw = aj[s] * wsel;
            rw[2 * j]      = aw * mwy0;
            rix[2 * j]     = (st + yc0 * Wl + bx) * 32;
            rw[2 * j + 1]  = aw * mwy1;
            rix[2 * j + 1] = (st + yc1 * Wl + bx) * 32;
        }

        #pragma unroll
        for (int r = 0; r < 8; r++) {
            const uint4 u = *(const uint4*)(vb + rix[r]);
            const f32x2 w2 = {rw[r], rw[r]};
            acc[0] += w2 * __builtin_amdgcn_cvt_pk_f32_fp8((int)u.x, false);
            acc[1] += w2 * __builtin_amdgcn_cvt_pk_f32_fp8((int)u.x, true);
            acc[2] += w2 * __builtin_amdgcn_cvt_pk_f32_fp8((int)u.y, false);
            acc[3] += w2 * __builtin_amdgcn_cvt_pk_f32_fp8((int)u.y, true);
            acc[4] += w2 * __builtin_amdgcn_cvt_pk_f32_fp8((int)u.z, false);
            acc[5] += w2 * __builtin_amdgcn_cvt_pk_f32_fp8((int)u.z, true);
            acc[6] += w2 * __builtin_amdgcn_cvt_pk_f32_fp8((int)u.w, false);
            acc[7] += w2 * __builtin_amdgcn_cvt_pk_f32_fp8((int)u.w, true);
        }
    }

    #pragma unroll
    for (int k = 0; k < 8; k++) {
        acc[k].x += __shfl_xor(acc[k].x, 2);
        acc[k].y += __shfl_xor(acc[k].y, 2);
    }

    f32x2 r0, r1, r2, r3;
    if (half == 0) { r0 = acc[0]; r1 = acc[1]; r2 = acc[2]; r3 = acc[3]; }
    else           { r0 = acc[4]; r1 = acc[5]; r2 = acc[6]; r3 = acc[7]; }

    const int ch_start = (cg & 1) * 16 + half * 8;
    uint4 o;
    o.x = (uint)f2bf(r0.x) | ((uint)f2bf(r0.y) << 16);
    o.y = (uint)f2bf(r1.x) | ((uint)f2bf(r1.y) << 16);
    o.z = (uint)f2bf(r2.x) | ((uint)f2bf(r2.y) << 16);
    o.w = (uint)f2bf(r3.x) | ((uint)f2bf(r3.y) << 16);
    *(uint4*)(samp + (size_t)q * 256 + h * 32 + ch_start) = o;
}

// ---------------------------------------------------------------------------
extern "C" void kernel_launch(void* const* d_in, const int* in_sizes, int n_in,
                              void* d_out, int out_size, void* d_ws, size_t ws_size,
                              hipStream_t stream)
{
    const float* src    = (const float*)d_in[0];
    const float* pos    = (const float*)d_in[1];
    const float* refp   = (const float*)d_in[2];
    const float* W_off  = (const float*)d_in[5];
    const float* b_off  = (const float*)d_in[6];
    const float* W_attn = (const float*)d_in[7];
    const float* b_attn = (const float*)d_in[8];
    const float* W_val  = (const float*)d_in[9];
    const float* b_val  = (const float*)d_in[10];
    const float* W_out  = (const float*)d_in[11];
    const float* b_out  = (const float*)d_in[12];
    const float* g1     = (const float*)d_in[13];
    const float* be1    = (const float*)d_in[14];
    const float* W_ff1  = (const float*)d_in[15];
    const float* b_ff1  = (const float*)d_in[16];
    const float* W_ff2  = (const float*)d_in[17];
    const float* b_ff2  = (const float*)d_in[18];
    const float* g2     = (const float*)d_in[19];
    const float* be2    = (const float*)d_in[20];
    float* out = (float*)d_out;

    const size_t szMDh = (size_t)M_ * 256 * 2;      // 22,282,240 B
    const size_t szOAh = (size_t)M_ * 384 * 2;      // 33,423,360 B

    char* ws = (char*)d_ws;
    ushort* WT      = (ushort*)ws;
    ushort* WT_val  = WT;
    ushort* WT_oa   = WT + 65536;
    ushort* WT_out  = WT + 163840;
    ushort* WT_ff1  = WT + 229376;
    ushort* WT_ff2  = WT + 491520;
    float*  bias_oa = (float*)(ws + 1507328);

    const size_t o_src  = 2097152;                  // src_bf  -> samp, hbuf
    const size_t o_q    = o_src + szMDh;            // q_bf
    const size_t o_val  = o_q   + szMDh;            // value (fp8 head-major)
    const size_t o_oa   = o_val + szMDh;            // offaw [M][384]
    const size_t o_x    = o_oa  + szOAh;            // x_bf

    ushort* src_bf = (ushort*)(ws + o_src);
    ushort* q_bf   = (ushort*)(ws + o_q);
    ushort* val_f8 = (ushort*)(ws + o_val);
    ushort* offaw  = (ushort*)(ws + o_oa);
    ushort* x_bf   = (ushort*)(ws + o_x);
    ushort* samp_bf = src_bf;   // src_bf dead after value GEMM
    // hbuf needs M*1024*2 = 89.1 MB; ff1 runs after the attn-out GEMM+LN,
    // so src..oa (src+q+val+offaw = 100.3 MB) is free by then.
    ushort* hbuf    = src_bf;

    // 0) all weight converts + bias concat
    wconv_all<<<(753664 + 384 + 255) / 256, 256, 0, stream>>>(
        W_val, W_off, W_attn, W_out, W_ff1, W_ff2, b_off, b_attn, WT, bias_oa);
    // 1) activation converts
    cvt_pair<<<(M_ * 256 / 4 + 255) / 256, 256, 0, stream>>>(src, pos, src_bf, q_bf);
    // 2) value = src @ W_val + b_val  (fp8 head-major output)
    mgemm<<<dim3(2, M_ / 128), 256, 0, stream>>>(src_bf, WT_val, b_val, val_f8, M_, 256, 256, 0, 2);
    // 3) offaw = (src+pos) @ [W_off|W_attn] + [b_off|b_attn]
    mgemm<<<dim3(3, M_ / 128), 256, 0, stream>>>(q_bf, WT_oa, bias_oa, offaw, M_, 384, 256, 0, 0);
    // 4) sampling
    sample6<<<M_ / 8, 256, 0, stream>>>((const uint8_t*)val_f8, offaw, refp, samp_bf);
    // 5) x = LN(src + samp @ W_out + b_out)   [fused GEMM+residual+LN v2]
    mgemm_ln<<<M_ / 64, 256, 0, stream>>>(samp_bf, WT_out, b_out,
                                          src, nullptr, g1, be1,
                                          nullptr, x_bf, 256);
    // 6) FFN1: h = relu(x @ W_ff1 + b_ff1)
    mgemm<<<dim3(8, M_ / 128), 256, 0, stream>>>(x_bf, WT_ff1, b_ff1, hbuf, M_, DFF_, 256, 1, 0);
    // 7) out = LN(x + h @ W_ff2 + b_ff2)      [fused GEMM+residual+LN v2]
    mgemm_ln<<<M_ / 64, 256, 0, stream>>>(hbuf, WT_ff2, b_ff2,
                                          nullptr, x_bf, g2, be2,
                                          out, nullptr, DFF_);
}

// Round 9
// 292.874 us; speedup vs baseline: 1.1469x; 1.0810x over previous
//
#include <hip/hip_runtime.h>
#include <cstdint>
#include <cstddef>

#define B_   2
#define S_   21760
#define M_   (B_ * S_)     // 43520
#define D_   256
#define DFF_ 1024
#define EPS_ 1e-5f

typedef __attribute__((ext_vector_type(8))) short short8;
typedef __attribute__((ext_vector_type(4))) float f32x4;
typedef __attribute__((ext_vector_type(2))) float f32x2;

__device__ __forceinline__ ushort f2bf(float f) {
    uint x = __float_as_uint(f);
    return (ushort)((x + 0x7fffu + ((x >> 16) & 1u)) >> 16);
}
__device__ __forceinline__ float bf2f(ushort u) {
    return __uint_as_float(((uint)u) << 16);
}

// ---------------------------------------------------------------------------
// One-shot weight transpose+convert for ALL weights + off/attn bias concat.
// ---------------------------------------------------------------------------
__global__ __launch_bounds__(256) void wconv_all(
    const float* __restrict__ Wval, const float* __restrict__ Woff,
    const float* __restrict__ Wattn, const float* __restrict__ Wout,
    const float* __restrict__ Wff1, const float* __restrict__ Wff2,
    const float* __restrict__ boff, const float* __restrict__ battn,
    ushort* __restrict__ WT, float* __restrict__ bias_oa)
{
    const int i = blockIdx.x * 256 + threadIdx.x;
    if (i < 65536) {
        const int n = i >> 8, k = i & 255;
        WT[i] = f2bf(Wval[(size_t)k * 256 + n]);
    } else if (i < 163840) {
        const int j = i - 65536;
        const int n = j >> 8, k = j & 255;
        WT[i] = (n < 256) ? f2bf(Woff[(size_t)k * 256 + n])
                          : f2bf(Wattn[(size_t)k * 128 + (n - 256)]);
    } else if (i < 229376) {
        const int j = i - 163840;
        const int n = j >> 8, k = j & 255;
        WT[i] = f2bf(Wout[(size_t)k * 256 + n]);
    } else if (i < 491520) {
        const int j = i - 229376;
        const int n = j >> 8, k = j & 255;
        WT[i] = f2bf(Wff1[(size_t)k * 1024 + n]);
    } else if (i < 753664) {
        const int j = i - 491520;
        const int n = j >> 10, k = j & 1023;
        WT[i] = f2bf(Wff2[(size_t)k * 256 + n]);
    } else if (i < 753664 + 384) {
        const int j = i - 753664;
        bias_oa[j] = (j < 256) ? boff[j] : battn[j - 256];
    }
}

// ---------------------------------------------------------------------------
// src_bf = bf16(src); q_bf = bf16(src + pos)
// ---------------------------------------------------------------------------
__global__ __launch_bounds__(256) void cvt_pair(
    const float* __restrict__ src, const float* __restrict__ pos,
    ushort* __restrict__ sb, ushort* __restrict__ qb)
{
    const size_t i = ((size_t)blockIdx.x * 256 + threadIdx.x) * 4;
    if (i >= (size_t)M_ * 256) return;
    const float4 s = *(const float4*)(src + i);
    const float4 p = *(const float4*)(pos + i);
    ushort4 so, qo;
    so.x = f2bf(s.x); so.y = f2bf(s.y); so.z = f2bf(s.z); so.w = f2bf(s.w);
    qo.x = f2bf(s.x + p.x); qo.y = f2bf(s.y + p.y);
    qo.z = f2bf(s.z + p.z); qo.w = f2bf(s.w + p.w);
    *(ushort4*)(sb + i) = so;
    *(ushort4*)(qb + i) = qo;
}

// ---------------------------------------------------------------------------
// bf16 MFMA GEMM: 128x128 tile, BK=32, 4 waves, 4x4 16x16x32 fragments.
// mode 0: C row-major [M][N] bf16.   mode 2: C fp8 e4m3 head-major value.
// ---------------------------------------------------------------------------
__global__ __launch_bounds__(256) void mgemm(
    const ushort* __restrict__ A, const ushort* __restrict__ WT,
    const float* __restrict__ bias, ushort* __restrict__ C,
    int M, int N, int K, int relu, int mode)
{
    __shared__ __align__(16) ushort Als[128 * 32];
    __shared__ __align__(16) ushort Bls[128 * 32];

    const int tid = threadIdx.x;
    const int wv = tid >> 6, ln = tid & 63;
    const int m0 = blockIdx.y << 7, n0 = blockIdx.x << 7;
    const int wm = wv >> 1, wn = wv & 1;

    const int lrow = ln >> 2, lcol = (ln & 3) * 8;

    f32x4 acc[4][4];
    const f32x4 zz = {0.f, 0.f, 0.f, 0.f};
    #pragma unroll
    for (int i = 0; i < 4; i++)
        #pragma unroll
        for (int j = 0; j < 4; j++) acc[i][j] = zz;

    for (int k0 = 0; k0 < K; k0 += 32) {
        __syncthreads();
        #pragma unroll
        for (int r = 0; r < 2; ++r) {
            const int c = r * 4 + wv;
            const ushort* ga = A + (size_t)(m0 + c * 16 + lrow) * K + k0 + lcol;
            __builtin_amdgcn_global_load_lds(
                (const __attribute__((address_space(1))) uint*)ga,
                (__attribute__((address_space(3))) uint*)(Als + c * 512), 16, 0, 0);
            const ushort* gb = WT + (size_t)(n0 + c * 16 + lrow) * K + k0 + lcol;
            __builtin_amdgcn_global_load_lds(
                (const __attribute__((address_space(1))) uint*)gb,
                (__attribute__((address_space(3))) uint*)(Bls + c * 512), 16, 0, 0);
        }
        __syncthreads();

        const int fr = ln & 15, kb = (ln >> 4) * 8;
        short8 af[4], bfr[4];
        #pragma unroll
        for (int i = 0; i < 4; i++)
            af[i] = *(const short8*)&Als[(wm * 64 + i * 16 + fr) * 32 + kb];
        #pragma unroll
        for (int j = 0; j < 4; j++)
            bfr[j] = *(const short8*)&Bls[(wn * 64 + j * 16 + fr) * 32 + kb];
        #pragma unroll
        for (int i = 0; i < 4; i++)
            #pragma unroll
            for (int j = 0; j < 4; j++)
                acc[i][j] = __builtin_amdgcn_mfma_f32_16x16x32_bf16(
                    af[i], bfr[j], acc[i][j], 0, 0, 0);
    }

    uint8_t* C8 = (uint8_t*)C;
    const int fr = ln & 15, rq = (ln >> 4) * 4;
    #pragma unroll
    for (int j = 0; j < 4; j++) {
        const int col = n0 + wn * 64 + j * 16 + fr;
        const float bv = bias[col];
        #pragma unroll
        for (int i = 0; i < 4; i++) {
            #pragma unroll
            for (int r = 0; r < 4; r++) {
                const int row = m0 + wm * 64 + i * 16 + rq + r;
                float v = acc[i][j][r] + bv;
                if (relu) v = fmaxf(v, 0.f);
                if (mode == 0) {
                    C[(size_t)row * N + col] = f2bf(v);
                } else {
                    const int bb = (row >= S_) ? 1 : 0;
                    const int loc = row - bb * S_;
                    const int hh = col >> 5, ch = col & 31;
                    const int pk = __builtin_amdgcn_cvt_pk_fp8_f32(v, v, 0, false);
                    C8[((size_t)(bb * 8 + hh) * S_ + loc) * 32 + ch] = (uint8_t)(pk & 0xff);
                }
            }
        }
    }
}

// ---------------------------------------------------------------------------
// Residual + LayerNorm, wave-per-row, fully vectorized, no LDS/barriers.
// 4 rows per 256-thread block; lane l owns cols 4l..4l+3.
// out = LN(bf(a16)+bf(r16)) * g + be ; output f32 (o32) or bf16 (o16).
// ---------------------------------------------------------------------------
__global__ __launch_bounds__(256) void ln_row(
    const ushort* __restrict__ a16, const ushort* __restrict__ r16,
    const float* __restrict__ g, const float* __restrict__ be,
    float* __restrict__ o32, ushort* __restrict__ o16)
{
    const int wv = threadIdx.x >> 6, ln = threadIdx.x & 63;
    const int row = blockIdx.x * 4 + wv;
    const int col = ln * 4;
    const size_t base = (size_t)row * 256 + col;

    const ushort4 av = *(const ushort4*)(a16 + base);
    const ushort4 rv = *(const ushort4*)(r16 + base);
    float v0 = bf2f(av.x) + bf2f(rv.x);
    float v1 = bf2f(av.y) + bf2f(rv.y);
    float v2 = bf2f(av.z) + bf2f(rv.z);
    float v3 = bf2f(av.w) + bf2f(rv.w);

    float s = v0 + v1 + v2 + v3;
    float s2 = v0 * v0 + v1 * v1 + v2 * v2 + v3 * v3;
    #pragma unroll
    for (int o = 32; o > 0; o >>= 1) {
        s  += __shfl_down(s, o);
        s2 += __shfl_down(s2, o);
    }
    s = __shfl(s, 0);
    s2 = __shfl(s2, 0);
    const float mean = s * (1.f / 256.f);
    const float var = s2 * (1.f / 256.f) - mean * mean;
    const float rstd = rsqrtf(var + EPS_);

    const float4 gv = *(const float4*)(g + col);
    const float4 bv = *(const float4*)(be + col);
    const float o0 = (v0 - mean) * rstd * gv.x + bv.x;
    const float o1 = (v1 - mean) * rstd * gv.y + bv.y;
    const float o2 = (v2 - mean) * rstd * gv.z + bv.z;
    const float o3 = (v3 - mean) * rstd * gv.w + bv.w;

    if (o32) {
        float4 o; o.x = o0; o.y = o1; o.z = o2; o.w = o3;
        *(float4*)(o32 + base) = o;
    } else {
        ushort4 o; o.x = f2bf(o0); o.y = f2bf(o1); o.z = f2bf(o2); o.w = f2bf(o3);
        *(ushort4*)(o16 + base) = o;
    }
}

// ---------------------------------------------------------------------------
// Deformable sampling v6: cooperative corner-PAIR (64B region) loads.
// ---------------------------------------------------------------------------
__global__ __launch_bounds__(256) void sample6(
    const uint8_t* __restrict__ value, const ushort* __restrict__ offaw,
    const float* __restrict__ refp, ushort* __restrict__ samp)
{
    const int nwg = M_ / 8;                       // 5440 (%8 == 0)
    const int bid = blockIdx.x;
    const int wg = (bid & 7) * (nwg >> 3) + (bid >> 3);

    const int t = threadIdx.x;
    const int q = wg * 8 + (t >> 5);
    const int w = t & 31;
    const int h = w >> 2, cg = w & 3;
    const int half = cg >> 1;
    const int b = q / S_;

    const ushort* awq = offaw + (size_t)q * 384 + 256 + h * 16;
    const uint4 la = *(const uint4*)awq;
    const uint4 lb = *(const uint4*)(awq + 8);
    const uint lgu[8] = {la.x, la.y, la.z, la.w, lb.x, lb.y, lb.z, lb.w};
    float aj[16];
    float mx = -1e30f;
    #pragma unroll
    for (int k = 0; k < 8; k++) {
        aj[2 * k]     = bf2f((ushort)(lgu[k] & 0xffff));
        aj[2 * k + 1] = bf2f((ushort)(lgu[k] >> 16));
        mx = fmaxf(mx, fmaxf(aj[2 * k], aj[2 * k + 1]));
    }
    float sum = 0.f;
    #pragma unroll
    for (int s = 0; s < 16; s++) { aj[s] = __expf(aj[s] - mx); sum += aj[s]; }
    const float inv = 1.f / sum;
    #pragma unroll
    for (int s = 0; s < 16; s++) aj[s] *= inv;

    const ushort* ofq = offaw + (size_t)q * 384 + h * 32;
    const uint4 o0 = *(const uint4*)ofq;
    const uint4 o1 = *(const uint4*)(ofq + 8);
    const uint4 o2 = *(const uint4*)(ofq + 16);
    const uint4 o3 = *(const uint4*)(ofq + 24);
    const uint ou[16] = {o0.x, o0.y, o0.z, o0.w, o1.x, o1.y, o1.z, o1.w,
                         o2.x, o2.y, o2.z, o2.w, o3.x, o3.y, o3.z, o3.w};
    const float* rp = refp + (size_t)q * 8;
    const float4 rpa = *(const float4*)rp;
    const float4 rpb = *(const float4*)(rp + 4);
    const float rxa[4] = {rpa.x, rpa.z, rpb.x, rpb.z};
    const float rya[4] = {rpa.y, rpa.w, rpb.y, rpb.w};
    const int   stv[4] = {0, 16384, 20480, 21504};

    const uint8_t* vb = value + (size_t)(b * 8 + h) * S_ * 32 + cg * 16;

    f32x2 acc[8];
    #pragma unroll
    for (int k = 0; k < 8; k++) acc[k] = (f32x2){0.f, 0.f};

    #pragma unroll
    for (int l = 0; l < 4; l++) {
        const int Wl = 128 >> l;
        const float fW = (float)Wl;
        const int st = stv[l];
        const float rx = rxa[l], ry = rya[l];

        float rw[8];
        int   rix[8];
        #pragma unroll
        for (int j = 0; j < 4; j++) {
            const int s = l * 4 + j;
            const float ox = bf2f((ushort)(ou[s] & 0xffff));
            const float oy = bf2f((ushort)(ou[s] >> 16));
            const float x = fmaf(rx, fW, ox) - 0.5f;
            const float y = fmaf(ry, fW, oy) - 0.5f;
            const float fx0 = floorf(x), fy0 = floorf(y);
            const float dx = x - fx0, dy = y - fy0;
            const int x0 = (int)fx0, y0 = (int)fy0;

            const int bx = min(max(x0, 0), Wl - 2);
            const float mwx0 = ((x0 >= 0) & (x0 < Wl)) ? (1.f - dx) : 0.f;
            const float mwx1 = ((x0 + 1 >= 0) & (x0 + 1 < Wl)) ? dx : 0.f;
            const int xc0 = min(max(x0, 0), Wl - 1);
            const int xc1 = min(max(x0 + 1, 0), Wl - 1);
            const float wAx = (xc0 == bx ? mwx0 : 0.f) + (xc1 == bx ? mwx1 : 0.f);
            const float wBx = (xc0 == bx + 1 ? mwx0 : 0.f) + (xc1 == bx + 1 ? mwx1 : 0.f);
            const float wsel = half ? wBx : wAx;

            const int yc0 = min(max(y0, 0), Wl - 1);
            const int yc1 = min(max(y0 + 1, 0), Wl - 1);
            const float mwy0 = ((y0 >= 0) & (y0 < Wl)) ? (1.f - dy) : 0.f;
            const float mwy1 = ((y0 + 1 >= 0) & (y0 + 1 < Wl)) ? dy : 0.f;

            const float aw = aj[s] * wsel;
            rw[2 * j]      = aw * mwy0;
            rix[2 * j]     = (st + yc0 * Wl + bx) * 32;
            rw[2 * j + 1]  = aw * mwy1;
            rix[2 * j + 1] = (st + yc1 * Wl + bx) * 32;
        }

        #pragma unroll
        for (int r = 0; r < 8; r++) {
            const uint4 u = *(const uint4*)(vb + rix[r]);
            const f32x2 w2 = {rw[r], rw[r]};
            acc[0] += w2 * __builtin_amdgcn_cvt_pk_f32_fp8((int)u.x, false);
            acc[1] += w2 * __builtin_amdgcn_cvt_pk_f32_fp8((int)u.x, true);
            acc[2] += w2 * __builtin_amdgcn_cvt_pk_f32_fp8((int)u.y, false);
            acc[3] += w2 * __builtin_amdgcn_cvt_pk_f32_fp8((int)u.y, true);
            acc[4] += w2 * __builtin_amdgcn_cvt_pk_f32_fp8((int)u.z, false);
            acc[5] += w2 * __builtin_amdgcn_cvt_pk_f32_fp8((int)u.z, true);
            acc[6] += w2 * __builtin_amdgcn_cvt_pk_f32_fp8((int)u.w, false);
            acc[7] += w2 * __builtin_amdgcn_cvt_pk_f32_fp8((int)u.w, true);
        }
    }

    #pragma unroll
    for (int k = 0; k < 8; k++) {
        acc[k].x += __shfl_xor(acc[k].x, 2);
        acc[k].y += __shfl_xor(acc[k].y, 2);
    }

    f32x2 r0, r1, r2, r3;
    if (half == 0) { r0 = acc[0]; r1 = acc[1]; r2 = acc[2]; r3 = acc[3]; }
    else           { r0 = acc[4]; r1 = acc[5]; r2 = acc[6]; r3 = acc[7]; }

    const int ch_start = (cg & 1) * 16 + half * 8;
    uint4 o;
    o.x = (uint)f2bf(r0.x) | ((uint)f2bf(r0.y) << 16);
    o.y = (uint)f2bf(r1.x) | ((uint)f2bf(r1.y) << 16);
    o.z = (uint)f2bf(r2.x) | ((uint)f2bf(r2.y) << 16);
    o.w = (uint)f2bf(r3.x) | ((uint)f2bf(r3.y) << 16);
    *(uint4*)(samp + (size_t)q * 256 + h * 32 + ch_start) = o;
}

// ---------------------------------------------------------------------------
extern "C" void kernel_launch(void* const* d_in, const int* in_sizes, int n_in,
                              void* d_out, int out_size, void* d_ws, size_t ws_size,
                              hipStream_t stream)
{
    const float* src    = (const float*)d_in[0];
    const float* pos    = (const float*)d_in[1];
    const float* refp   = (const float*)d_in[2];
    const float* W_off  = (const float*)d_in[5];
    const float* b_off  = (const float*)d_in[6];
    const float* W_attn = (const float*)d_in[7];
    const float* b_attn = (const float*)d_in[8];
    const float* W_val  = (const float*)d_in[9];
    const float* b_val  = (const float*)d_in[10];
    const float* W_out  = (const float*)d_in[11];
    const float* b_out  = (const float*)d_in[12];
    const float* g1     = (const float*)d_in[13];
    const float* be1    = (const float*)d_in[14];
    const float* W_ff1  = (const float*)d_in[15];
    const float* b_ff1  = (const float*)d_in[16];
    const float* W_ff2  = (const float*)d_in[17];
    const float* b_ff2  = (const float*)d_in[18];
    const float* g2     = (const float*)d_in[19];
    const float* be2    = (const float*)d_in[20];
    float* out = (float*)d_out;

    const size_t szMDh = (size_t)M_ * 256 * 2;      // 22,282,240 B
    const size_t szOAh = (size_t)M_ * 384 * 2;      // 33,423,360 B

    char* ws = (char*)d_ws;
    ushort* WT      = (ushort*)ws;
    ushort* WT_val  = WT;
    ushort* WT_oa   = WT + 65536;
    ushort* WT_out  = WT + 163840;
    ushort* WT_ff1  = WT + 229376;
    ushort* WT_ff2  = WT + 491520;
    float*  bias_oa = (float*)(ws + 1507328);

    // Buffer lifetimes (re-arranged so src_bf survives to LN1):
    //  o_src: src_bf  (live through ln1; then reused as hbuf start)
    //  o_q  : q_bf    (dead after offaw GEMM) -> samp_bf
    //  o_val: val_f8  (dead after sampling)   -> attn_bf
    //  o_oa : offaw   (dead after sampling)
    //  o_x  : x_bf    (live through ln2)
    //  o_ffn: ffn_bf  (tail)
    //  hbuf (89.1 MB) spans src+q+val+oa (100.3 MB), written after ln1.
    const size_t o_src  = 2097152;
    const size_t o_q    = o_src + szMDh;
    const size_t o_val  = o_q   + szMDh;
    const size_t o_oa   = o_val + szMDh;
    const size_t o_x    = o_oa  + szOAh;
    const size_t o_ffn  = o_x   + szMDh;            // total 146.9 MB (proven fit)

    ushort* src_bf  = (ushort*)(ws + o_src);
    ushort* q_bf    = (ushort*)(ws + o_q);
    ushort* val_f8  = (ushort*)(ws + o_val);
    ushort* offaw   = (ushort*)(ws + o_oa);
    ushort* x_bf    = (ushort*)(ws + o_x);
    ushort* ffn_bf  = (ushort*)(ws + o_ffn);
    ushort* samp_bf = q_bf;
    ushort* attn_bf = val_f8;
    ushort* hbuf    = src_bf;

    // 0) all weight converts + bias concat
    wconv_all<<<(753664 + 384 + 255) / 256, 256, 0, stream>>>(
        W_val, W_off, W_attn, W_out, W_ff1, W_ff2, b_off, b_attn, WT, bias_oa);
    // 1) activation converts
    cvt_pair<<<(M_ * 256 / 4 + 255) / 256, 256, 0, stream>>>(src, pos, src_bf, q_bf);
    // 2) value = src @ W_val + b_val  (fp8 head-major output)
    mgemm<<<dim3(2, M_ / 128), 256, 0, stream>>>(src_bf, WT_val, b_val, val_f8, M_, 256, 256, 0, 2);
    // 3) offaw = (src+pos) @ [W_off|W_attn] + [b_off|b_attn]
    mgemm<<<dim3(3, M_ / 128), 256, 0, stream>>>(q_bf, WT_oa, bias_oa, offaw, M_, 384, 256, 0, 0);
    // 4) sampling (writes into q region; q_bf dead)
    sample6<<<M_ / 8, 256, 0, stream>>>((const uint8_t*)val_f8, offaw, refp, samp_bf);
    // 5) attn_out = samp @ W_out + b_out (into val region; val dead)
    mgemm<<<dim3(2, M_ / 128), 256, 0, stream>>>(samp_bf, WT_out, b_out, attn_bf, M_, 256, 256, 0, 0);
    // 6) x = LN(src_bf + attn)
    ln_row<<<M_ / 4, 256, 0, stream>>>(attn_bf, src_bf, g1, be1, nullptr, x_bf);
    // 7) FFN1: h = relu(x @ W_ff1 + b_ff1)  (hbuf overwrites src..oa; all dead)
    mgemm<<<dim3(8, M_ / 128), 256, 0, stream>>>(x_bf, WT_ff1, b_ff1, hbuf, M_, DFF_, 256, 1, 0);
    // 8) FFN2: ffn = h @ W_ff2 + b_ff2
    mgemm<<<dim3(2, M_ / 128), 256, 0, stream>>>(hbuf, WT_ff2, b_ff2, ffn_bf, M_, 256, DFF_, 0, 0);
    // 9) out = LN(x + ffn)  (f32 output)
    ln_row<<<M_ / 4, 256, 0, stream>>>(ffn_bf, x_bf, g2, be2, out, nullptr);
}

// Round 10
// 274.568 us; speedup vs baseline: 1.2233x; 1.0667x over previous
//
#include <hip/hip_runtime.h>
#include <cstdint>
#include <cstddef>

#define B_   2
#define S_   21760
#define M_   (B_ * S_)     // 43520
#define D_   256
#define DFF_ 1024
#define EPS_ 1e-5f

typedef __attribute__((ext_vector_type(8))) short short8;
typedef __attribute__((ext_vector_type(4))) float f32x4;
typedef __attribute__((ext_vector_type(2))) float f32x2;

__device__ __forceinline__ ushort f2bf(float f) {
    uint x = __float_as_uint(f);
    return (ushort)((x + 0x7fffu + ((x >> 16) & 1u)) >> 16);
}
__device__ __forceinline__ float bf2f(ushort u) {
    return __uint_as_float(((uint)u) << 16);
}

// ---------------------------------------------------------------------------
// Merged prep: blocks [0,10880) do src/q bf16 converts; rest do weight
// transpose+convert + bias concat (one dispatch total).
// ---------------------------------------------------------------------------
#define CVT_BLOCKS 10880
__global__ __launch_bounds__(256) void prep_all(
    const float* __restrict__ src, const float* __restrict__ pos,
    ushort* __restrict__ sb, ushort* __restrict__ qb,
    const float* __restrict__ Wval, const float* __restrict__ Woff,
    const float* __restrict__ Wattn, const float* __restrict__ Wout,
    const float* __restrict__ Wff1, const float* __restrict__ Wff2,
    const float* __restrict__ boff, const float* __restrict__ battn,
    ushort* __restrict__ WT, float* __restrict__ bias_oa)
{
    if (blockIdx.x < CVT_BLOCKS) {
        const size_t i = ((size_t)blockIdx.x * 256 + threadIdx.x) * 4;
        const float4 s = *(const float4*)(src + i);
        const float4 p = *(const float4*)(pos + i);
        ushort4 so, qo;
        so.x = f2bf(s.x); so.y = f2bf(s.y); so.z = f2bf(s.z); so.w = f2bf(s.w);
        qo.x = f2bf(s.x + p.x); qo.y = f2bf(s.y + p.y);
        qo.z = f2bf(s.z + p.z); qo.w = f2bf(s.w + p.w);
        *(ushort4*)(sb + i) = so;
        *(ushort4*)(qb + i) = qo;
        return;
    }
    const int i = (blockIdx.x - CVT_BLOCKS) * 256 + threadIdx.x;
    if (i < 65536) {
        const int n = i >> 8, k = i & 255;
        WT[i] = f2bf(Wval[(size_t)k * 256 + n]);
    } else if (i < 163840) {
        const int j = i - 65536;
        const int n = j >> 8, k = j & 255;
        WT[i] = (n < 256) ? f2bf(Woff[(size_t)k * 256 + n])
                          : f2bf(Wattn[(size_t)k * 128 + (n - 256)]);
    } else if (i < 229376) {
        const int j = i - 163840;
        const int n = j >> 8, k = j & 255;
        WT[i] = f2bf(Wout[(size_t)k * 256 + n]);
    } else if (i < 491520) {
        const int j = i - 229376;
        const int n = j >> 8, k = j & 255;
        WT[i] = f2bf(Wff1[(size_t)k * 1024 + n]);
    } else if (i < 753664) {
        const int j = i - 491520;
        const int n = j >> 10, k = j & 1023;
        WT[i] = f2bf(Wff2[(size_t)k * 256 + n]);
    } else if (i < 753664 + 384) {
        const int j = i - 753664;
        bias_oa[j] = (j < 256) ? boff[j] : battn[j - 256];
    }
}

// ---------------------------------------------------------------------------
// bf16 MFMA GEMM: 128x128 tile, BK=32, 4 waves, 4x4 16x16x32 fragments.
// 1D grid with bijective XCD-chunked swizzle (m204): each XCD owns a
// contiguous M-chunk x all N-blocks -> A row-panels fetched once per XCD,
// B panels L2-resident. mode 0: C row-major bf16. mode 2: fp8 head-major.
// ---------------------------------------------------------------------------
__global__ __launch_bounds__(256) void mgemm(
    const ushort* __restrict__ A, const ushort* __restrict__ WT,
    const float* __restrict__ bias, ushort* __restrict__ C,
    int M, int N, int K, int relu, int mode)
{
    __shared__ __align__(16) ushort Als[128 * 32];
    __shared__ __align__(16) ushort Bls[128 * 32];

    // XCD-chunked bijective swizzle
    const int nwg = gridDim.x;
    const int bid = blockIdx.x;
    const int q8 = nwg >> 3, r8 = nwg & 7;
    const int xcd = bid & 7, blk = bid >> 3;
    const int wg = (xcd < r8 ? xcd * (q8 + 1) : r8 * (q8 + 1) + (xcd - r8) * q8) + blk;
    const int gx = N >> 7;
    const int n0 = (wg % gx) << 7;
    const int m0 = (wg / gx) << 7;

    const int tid = threadIdx.x;
    const int wv = tid >> 6, ln = tid & 63;
    const int wm = wv >> 1, wn = wv & 1;

    const int lrow = ln >> 2, lcol = (ln & 3) * 8;

    f32x4 acc[4][4];
    const f32x4 zz = {0.f, 0.f, 0.f, 0.f};
    #pragma unroll
    for (int i = 0; i < 4; i++)
        #pragma unroll
        for (int j = 0; j < 4; j++) acc[i][j] = zz;

    for (int k0 = 0; k0 < K; k0 += 32) {
        __syncthreads();
        #pragma unroll
        for (int r = 0; r < 2; ++r) {
            const int c = r * 4 + wv;
            const ushort* ga = A + (size_t)(m0 + c * 16 + lrow) * K + k0 + lcol;
            __builtin_amdgcn_global_load_lds(
                (const __attribute__((address_space(1))) uint*)ga,
                (__attribute__((address_space(3))) uint*)(Als + c * 512), 16, 0, 0);
            const ushort* gb = WT + (size_t)(n0 + c * 16 + lrow) * K + k0 + lcol;
            __builtin_amdgcn_global_load_lds(
                (const __attribute__((address_space(1))) uint*)gb,
                (__attribute__((address_space(3))) uint*)(Bls + c * 512), 16, 0, 0);
        }
        __syncthreads();

        const int fr = ln & 15, kb = (ln >> 4) * 8;
        short8 af[4], bfr[4];
        #pragma unroll
        for (int i = 0; i < 4; i++)
            af[i] = *(const short8*)&Als[(wm * 64 + i * 16 + fr) * 32 + kb];
        #pragma unroll
        for (int j = 0; j < 4; j++)
            bfr[j] = *(const short8*)&Bls[(wn * 64 + j * 16 + fr) * 32 + kb];
        #pragma unroll
        for (int i = 0; i < 4; i++)
            #pragma unroll
            for (int j = 0; j < 4; j++)
                acc[i][j] = __builtin_amdgcn_mfma_f32_16x16x32_bf16(
                    af[i], bfr[j], acc[i][j], 0, 0, 0);
    }

    uint8_t* C8 = (uint8_t*)C;
    const int fr = ln & 15, rq = (ln >> 4) * 4;
    #pragma unroll
    for (int j = 0; j < 4; j++) {
        const int col = n0 + wn * 64 + j * 16 + fr;
        const float bv = bias[col];
        #pragma unroll
        for (int i = 0; i < 4; i++) {
            #pragma unroll
            for (int r = 0; r < 4; r++) {
                const int row = m0 + wm * 64 + i * 16 + rq + r;
                float v = acc[i][j][r] + bv;
                if (relu) v = fmaxf(v, 0.f);
                if (mode == 0) {
                    C[(size_t)row * N + col] = f2bf(v);
                } else {
                    const int bb = (row >= S_) ? 1 : 0;
                    const int loc = row - bb * S_;
                    const int hh = col >> 5, ch = col & 31;
                    const int pk = __builtin_amdgcn_cvt_pk_fp8_f32(v, v, 0, false);
                    C8[((size_t)(bb * 8 + hh) * S_ + loc) * 32 + ch] = (uint8_t)(pk & 0xff);
                }
            }
        }
    }
}

// ---------------------------------------------------------------------------
// Residual + LayerNorm, wave-per-row, vectorized, no LDS/barriers.
// ---------------------------------------------------------------------------
__global__ __launch_bounds__(256) void ln_row(
    const ushort* __restrict__ a16, const ushort* __restrict__ r16,
    const float* __restrict__ g, const float* __restrict__ be,
    float* __restrict__ o32, ushort* __restrict__ o16)
{
    const int wv = threadIdx.x >> 6, ln = threadIdx.x & 63;
    const int row = blockIdx.x * 4 + wv;
    const int col = ln * 4;
    const size_t base = (size_t)row * 256 + col;

    const ushort4 av = *(const ushort4*)(a16 + base);
    const ushort4 rv = *(const ushort4*)(r16 + base);
    float v0 = bf2f(av.x) + bf2f(rv.x);
    float v1 = bf2f(av.y) + bf2f(rv.y);
    float v2 = bf2f(av.z) + bf2f(rv.z);
    float v3 = bf2f(av.w) + bf2f(rv.w);

    float s = v0 + v1 + v2 + v3;
    float s2 = v0 * v0 + v1 * v1 + v2 * v2 + v3 * v3;
    #pragma unroll
    for (int o = 32; o > 0; o >>= 1) {
        s  += __shfl_down(s, o);
        s2 += __shfl_down(s2, o);
    }
    s = __shfl(s, 0);
    s2 = __shfl(s2, 0);
    const float mean = s * (1.f / 256.f);
    const float var = s2 * (1.f / 256.f) - mean * mean;
    const float rstd = rsqrtf(var + EPS_);

    const float4 gv = *(const float4*)(g + col);
    const float4 bv = *(const float4*)(be + col);
    const float o0 = (v0 - mean) * rstd * gv.x + bv.x;
    const float o1 = (v1 - mean) * rstd * gv.y + bv.y;
    const float o2 = (v2 - mean) * rstd * gv.z + bv.z;
    const float o3 = (v3 - mean) * rstd * gv.w + bv.w;

    if (o32) {
        float4 o; o.x = o0; o.y = o1; o.z = o2; o.w = o3;
        *(float4*)(o32 + base) = o;
    } else {
        ushort4 o; o.x = f2bf(o0); o.y = f2bf(o1); o.z = f2bf(o2); o.w = f2bf(o3);
        *(ushort4*)(o16 + base) = o;
    }
}

// ---------------------------------------------------------------------------
// Deformable sampling v6: cooperative corner-PAIR (64B region) loads.
// ---------------------------------------------------------------------------
__global__ __launch_bounds__(256) void sample6(
    const uint8_t* __restrict__ value, const ushort* __restrict__ offaw,
    const float* __restrict__ refp, ushort* __restrict__ samp)
{
    const int nwg = M_ / 8;                       // 5440 (%8 == 0)
    const int bid = blockIdx.x;
    const int wg = (bid & 7) * (nwg >> 3) + (bid >> 3);

    const int t = threadIdx.x;
    const int q = wg * 8 + (t >> 5);
    const int w = t & 31;
    const int h = w >> 2, cg = w & 3;
    const int half = cg >> 1;
    const int b = q / S_;

    const ushort* awq = offaw + (size_t)q * 384 + 256 + h * 16;
    const uint4 la = *(const uint4*)awq;
    const uint4 lb = *(const uint4*)(awq + 8);
    const uint lgu[8] = {la.x, la.y, la.z, la.w, lb.x, lb.y, lb.z, lb.w};
    float aj[16];
    float mx = -1e30f;
    #pragma unroll
    for (int k = 0; k < 8; k++) {
        aj[2 * k]     = bf2f((ushort)(lgu[k] & 0xffff));
        aj[2 * k + 1] = bf2f((ushort)(lgu[k] >> 16));
        mx = fmaxf(mx, fmaxf(aj[2 * k], aj[2 * k + 1]));
    }
    float sum = 0.f;
    #pragma unroll
    for (int s = 0; s < 16; s++) { aj[s] = __expf(aj[s] - mx); sum += aj[s]; }
    const float inv = 1.f / sum;
    #pragma unroll
    for (int s = 0; s < 16; s++) aj[s] *= inv;

    const ushort* ofq = offaw + (size_t)q * 384 + h * 32;
    const uint4 o0 = *(const uint4*)ofq;
    const uint4 o1 = *(const uint4*)(ofq + 8);
    const uint4 o2 = *(const uint4*)(ofq + 16);
    const uint4 o3 = *(const uint4*)(ofq + 24);
    const uint ou[16] = {o0.x, o0.y, o0.z, o0.w, o1.x, o1.y, o1.z, o1.w,
                         o2.x, o2.y, o2.z, o2.w, o3.x, o3.y, o3.z, o3.w};
    const float* rp = refp + (size_t)q * 8;
    const float4 rpa = *(const float4*)rp;
    const float4 rpb = *(const float4*)(rp + 4);
    const float rxa[4] = {rpa.x, rpa.z, rpb.x, rpb.z};
    const float rya[4] = {rpa.y, rpa.w, rpb.y, rpb.w};
    const int   stv[4] = {0, 16384, 20480, 21504};

    const uint8_t* vb = value + (size_t)(b * 8 + h) * S_ * 32 + cg * 16;

    f32x2 acc[8];
    #pragma unroll
    for (int k = 0; k < 8; k++) acc[k] = (f32x2){0.f, 0.f};

    #pragma unroll
    for (int l = 0; l < 4; l++) {
        const int Wl = 128 >> l;
        const float fW = (float)Wl;
        const int st = stv[l];
        const float rx = rxa[l], ry = rya[l];

        float rw[8];
        int   rix[8];
        #pragma unroll
        for (int j = 0; j < 4; j++) {
            const int s = l * 4 + j;
            const float ox = bf2f((ushort)(ou[s] & 0xffff));
            const float oy = bf2f((ushort)(ou[s] >> 16));
            const float x = fmaf(rx, fW, ox) - 0.5f;
            const float y = fmaf(ry, fW, oy) - 0.5f;
            const float fx0 = floorf(x), fy0 = floorf(y);
            const float dx = x - fx0, dy = y - fy0;
            const int x0 = (int)fx0, y0 = (int)fy0;

            const int bx = min(max(x0, 0), Wl - 2);
            const float mwx0 = ((x0 >= 0) & (x0 < Wl)) ? (1.f - dx) : 0.f;
            const float mwx1 = ((x0 + 1 >= 0) & (x0 + 1 < Wl)) ? dx : 0.f;
            const int xc0 = min(max(x0, 0), Wl - 1);
            const int xc1 = min(max(x0 + 1, 0), Wl - 1);
            const float wAx = (xc0 == bx ? mwx0 : 0.f) + (xc1 == bx ? mwx1 : 0.f);
            const float wBx = (xc0 == bx + 1 ? mwx0 : 0.f) + (xc1 == bx + 1 ? mwx1 : 0.f);
            const float wsel = half ? wBx : wAx;

            const int yc0 = min(max(y0, 0), Wl - 1);
            const int yc1 = min(max(y0 + 1, 0), Wl - 1);
            const float mwy0 = ((y0 >= 0) & (y0 < Wl)) ? (1.f - dy) : 0.f;
            const float mwy1 = ((y0 + 1 >= 0) & (y0 + 1 < Wl)) ? dy : 0.f;

            const float aw = aj[s] * wsel;
            rw[2 * j]      = aw * mwy0;
            rix[2 * j]     = (st + yc0 * Wl + bx) * 32;
            rw[2 * j + 1]  = aw * mwy1;
            rix[2 * j + 1] = (st + yc1 * Wl + bx) * 32;
        }

        #pragma unroll
        for (int r = 0; r < 8; r++) {
            const uint4 u = *(const uint4*)(vb + rix[r]);
            const f32x2 w2 = {rw[r], rw[r]};
            acc[0] += w2 * __builtin_amdgcn_cvt_pk_f32_fp8((int)u.x, false);
            acc[1] += w2 * __builtin_amdgcn_cvt_pk_f32_fp8((int)u.x, true);
            acc[2] += w2 * __builtin_amdgcn_cvt_pk_f32_fp8((int)u.y, false);
            acc[3] += w2 * __builtin_amdgcn_cvt_pk_f32_fp8((int)u.y, true);
            acc[4] += w2 * __builtin_amdgcn_cvt_pk_f32_fp8((int)u.z, false);
            acc[5] += w2 * __builtin_amdgcn_cvt_pk_f32_fp8((int)u.z, true);
            acc[6] += w2 * __builtin_amdgcn_cvt_pk_f32_fp8((int)u.w, false);
            acc[7] += w2 * __builtin_amdgcn_cvt_pk_f32_fp8((int)u.w, true);
        }
    }

    #pragma unroll
    for (int k = 0; k < 8; k++) {
        acc[k].x += __shfl_xor(acc[k].x, 2);
        acc[k].y += __shfl_xor(acc[k].y, 2);
    }

    f32x2 r0, r1, r2, r3;
    if (half == 0) { r0 = acc[0]; r1 = acc[1]; r2 = acc[2]; r3 = acc[3]; }
    else           { r0 = acc[4]; r1 = acc[5]; r2 = acc[6]; r3 = acc[7]; }

    const int ch_start = (cg & 1) * 16 + half * 8;
    uint4 o;
    o.x = (uint)f2bf(r0.x) | ((uint)f2bf(r0.y) << 16);
    o.y = (uint)f2bf(r1.x) | ((uint)f2bf(r1.y) << 16);
    o.z = (uint)f2bf(r2.x) | ((uint)f2bf(r2.y) << 16);
    o.w = (uint)f2bf(r3.x) | ((uint)f2bf(r3.y) << 16);
    *(uint4*)(samp + (size_t)q * 256 + h * 32 + ch_start) = o;
}

// ---------------------------------------------------------------------------
extern "C" void kernel_launch(void* const* d_in, const int* in_sizes, int n_in,
                              void* d_out, int out_size, void* d_ws, size_t ws_size,
                              hipStream_t stream)
{
    const float* src    = (const float*)d_in[0];
    const float* pos    = (const float*)d_in[1];
    const float* refp   = (const float*)d_in[2];
    const float* W_off  = (const float*)d_in[5];
    const float* b_off  = (const float*)d_in[6];
    const float* W_attn = (const float*)d_in[7];
    const float* b_attn = (const float*)d_in[8];
    const float* W_val  = (const float*)d_in[9];
    const float* b_val  = (const float*)d_in[10];
    const float* W_out  = (const float*)d_in[11];
    const float* b_out  = (const float*)d_in[12];
    const float* g1     = (const float*)d_in[13];
    const float* be1    = (const float*)d_in[14];
    const float* W_ff1  = (const float*)d_in[15];
    const float* b_ff1  = (const float*)d_in[16];
    const float* W_ff2  = (const float*)d_in[17];
    const float* b_ff2  = (const float*)d_in[18];
    const float* g2     = (const float*)d_in[19];
    const float* be2    = (const float*)d_in[20];
    float* out = (float*)d_out;

    const size_t szMDh = (size_t)M_ * 256 * 2;      // 22,282,240 B
    const size_t szOAh = (size_t)M_ * 384 * 2;      // 33,423,360 B

    char* ws = (char*)d_ws;
    ushort* WT      = (ushort*)ws;
    ushort* WT_val  = WT;
    ushort* WT_oa   = WT + 65536;
    ushort* WT_out  = WT + 163840;
    ushort* WT_ff1  = WT + 229376;
    ushort* WT_ff2  = WT + 491520;
    float*  bias_oa = (float*)(ws + 1507328);

    const size_t o_src  = 2097152;
    const size_t o_q    = o_src + szMDh;
    const size_t o_val  = o_q   + szMDh;
    const size_t o_oa   = o_val + szMDh;
    const size_t o_x    = o_oa  + szOAh;
    const size_t o_ffn  = o_x   + szMDh;            // total 146.9 MB (proven fit)

    ushort* src_bf  = (ushort*)(ws + o_src);
    ushort* q_bf    = (ushort*)(ws + o_q);
    ushort* val_f8  = (ushort*)(ws + o_val);
    ushort* offaw   = (ushort*)(ws + o_oa);
    ushort* x_bf    = (ushort*)(ws + o_x);
    ushort* ffn_bf  = (ushort*)(ws + o_ffn);
    ushort* samp_bf = q_bf;      // q_bf dead after offaw GEMM
    ushort* attn_bf = val_f8;    // val dead after sampling
    ushort* hbuf    = src_bf;    // src..oa free after ln1 (100.3 MB >= 89.1)

    // 0) converts (src/q) + all weight transposes, one dispatch
    prep_all<<<CVT_BLOCKS + 2947, 256, 0, stream>>>(
        src, pos, src_bf, q_bf,
        W_val, W_off, W_attn, W_out, W_ff1, W_ff2, b_off, b_attn, WT, bias_oa);
    // 1) value = src @ W_val + b_val  (fp8 head-major)
    mgemm<<<2 * (M_ / 128), 256, 0, stream>>>(src_bf, WT_val, b_val, val_f8, M_, 256, 256, 0, 2);
    // 2) offaw = (src+pos) @ [W_off|W_attn] + bias
    mgemm<<<3 * (M_ / 128), 256, 0, stream>>>(q_bf, WT_oa, bias_oa, offaw, M_, 384, 256, 0, 0);
    // 3) sampling
    sample6<<<M_ / 8, 256, 0, stream>>>((const uint8_t*)val_f8, offaw, refp, samp_bf);
    // 4) attn_out = samp @ W_out + b_out
    mgemm<<<2 * (M_ / 128), 256, 0, stream>>>(samp_bf, WT_out, b_out, attn_bf, M_, 256, 256, 0, 0);
    // 5) x = LN(src_bf + attn)
    ln_row<<<M_ / 4, 256, 0, stream>>>(attn_bf, src_bf, g1, be1, nullptr, x_bf);
    // 6) FFN1: h = relu(x @ W_ff1 + b_ff1)
    mgemm<<<8 * (M_ / 128), 256, 0, stream>>>(x_bf, WT_ff1, b_ff1, hbuf, M_, DFF_, 256, 1, 0);
    // 7) FFN2: ffn = h @ W_ff2 + b_ff2
    mgemm<<<2 * (M_ / 128), 256, 0, stream>>>(hbuf, WT_ff2, b_ff2, ffn_bf, M_, 256, DFF_, 0, 0);
    // 8) out = LN(x + ffn)
    ln_row<<<M_ / 4, 256, 0, stream>>>(ffn_bf, x_bf, g2, be2, out, nullptr);
}

// Round 11
// 272.316 us; speedup vs baseline: 1.2334x; 1.0083x over previous
//
#include <hip/hip_runtime.h>
#include <cstdint>
#include <cstddef>

#define B_   2
#define S_   21760
#define M_   (B_ * S_)     // 43520
#define D_   256
#define DFF_ 1024
#define EPS_ 1e-5f

typedef __attribute__((ext_vector_type(8))) short short8;
typedef __attribute__((ext_vector_type(4))) float f32x4;
typedef __attribute__((ext_vector_type(2))) float f32x2;

__device__ __forceinline__ ushort f2bf(float f) {
    uint x = __float_as_uint(f);
    return (ushort)((x + 0x7fffu + ((x >> 16) & 1u)) >> 16);
}
__device__ __forceinline__ float bf2f(ushort u) {
    return __uint_as_float(((uint)u) << 16);
}

// ---------------------------------------------------------------------------
// Merged prep: blocks [0,10880) do src/q bf16 converts; rest do weight
// transpose+convert + bias concat (one dispatch total).
// ---------------------------------------------------------------------------
#define CVT_BLOCKS 10880
__global__ __launch_bounds__(256) void prep_all(
    const float* __restrict__ src, const float* __restrict__ pos,
    ushort* __restrict__ sb, ushort* __restrict__ qb,
    const float* __restrict__ Wval, const float* __restrict__ Woff,
    const float* __restrict__ Wattn, const float* __restrict__ Wout,
    const float* __restrict__ Wff1, const float* __restrict__ Wff2,
    const float* __restrict__ boff, const float* __restrict__ battn,
    ushort* __restrict__ WT, float* __restrict__ bias_oa)
{
    if (blockIdx.x < CVT_BLOCKS) {
        const size_t i = ((size_t)blockIdx.x * 256 + threadIdx.x) * 4;
        const float4 s = *(const float4*)(src + i);
        const float4 p = *(const float4*)(pos + i);
        ushort4 so, qo;
        so.x = f2bf(s.x); so.y = f2bf(s.y); so.z = f2bf(s.z); so.w = f2bf(s.w);
        qo.x = f2bf(s.x + p.x); qo.y = f2bf(s.y + p.y);
        qo.z = f2bf(s.z + p.z); qo.w = f2bf(s.w + p.w);
        *(ushort4*)(sb + i) = so;
        *(ushort4*)(qb + i) = qo;
        return;
    }
    const int i = (blockIdx.x - CVT_BLOCKS) * 256 + threadIdx.x;
    if (i < 65536) {
        const int n = i >> 8, k = i & 255;
        WT[i] = f2bf(Wval[(size_t)k * 256 + n]);
    } else if (i < 163840) {
        const int j = i - 65536;
        const int n = j >> 8, k = j & 255;
        WT[i] = (n < 256) ? f2bf(Woff[(size_t)k * 256 + n])
                          : f2bf(Wattn[(size_t)k * 128 + (n - 256)]);
    } else if (i < 229376) {
        const int j = i - 163840;
        const int n = j >> 8, k = j & 255;
        WT[i] = f2bf(Wout[(size_t)k * 256 + n]);
    } else if (i < 491520) {
        const int j = i - 229376;
        const int n = j >> 8, k = j & 255;
        WT[i] = f2bf(Wff1[(size_t)k * 1024 + n]);
    } else if (i < 753664) {
        const int j = i - 491520;
        const int n = j >> 10, k = j & 1023;
        WT[i] = f2bf(Wff2[(size_t)k * 256 + n]);
    } else if (i < 753664 + 384) {
        const int j = i - 753664;
        bias_oa[j] = (j < 256) ? boff[j] : battn[j - 256];
    }
}

// ---------------------------------------------------------------------------
// bf16 MFMA GEMM: 128x128 tile, BK=32, 4 waves, 4x4 16x16x32 fragments.
// 1D grid with bijective XCD-chunked swizzle. mode 0: bf16 row-major.
// mode 2: fp8 e4m3 head-major value layout.
// ---------------------------------------------------------------------------
__global__ __launch_bounds__(256) void mgemm(
    const ushort* __restrict__ A, const ushort* __restrict__ WT,
    const float* __restrict__ bias, ushort* __restrict__ C,
    int M, int N, int K, int relu, int mode)
{
    __shared__ __align__(16) ushort Als[128 * 32];
    __shared__ __align__(16) ushort Bls[128 * 32];

    const int nwg = gridDim.x;
    const int bid = blockIdx.x;
    const int q8 = nwg >> 3, r8 = nwg & 7;
    const int xcd = bid & 7, blk = bid >> 3;
    const int wg = (xcd < r8 ? xcd * (q8 + 1) : r8 * (q8 + 1) + (xcd - r8) * q8) + blk;
    const int gx = N >> 7;
    const int n0 = (wg % gx) << 7;
    const int m0 = (wg / gx) << 7;

    const int tid = threadIdx.x;
    const int wv = tid >> 6, ln = tid & 63;
    const int wm = wv >> 1, wn = wv & 1;

    const int lrow = ln >> 2, lcol = (ln & 3) * 8;

    f32x4 acc[4][4];
    const f32x4 zz = {0.f, 0.f, 0.f, 0.f};
    #pragma unroll
    for (int i = 0; i < 4; i++)
        #pragma unroll
        for (int j = 0; j < 4; j++) acc[i][j] = zz;

    for (int k0 = 0; k0 < K; k0 += 32) {
        __syncthreads();
        #pragma unroll
        for (int r = 0; r < 2; ++r) {
            const int c = r * 4 + wv;
            const ushort* ga = A + (size_t)(m0 + c * 16 + lrow) * K + k0 + lcol;
            __builtin_amdgcn_global_load_lds(
                (const __attribute__((address_space(1))) uint*)ga,
                (__attribute__((address_space(3))) uint*)(Als + c * 512), 16, 0, 0);
            const ushort* gb = WT + (size_t)(n0 + c * 16 + lrow) * K + k0 + lcol;
            __builtin_amdgcn_global_load_lds(
                (const __attribute__((address_space(1))) uint*)gb,
                (__attribute__((address_space(3))) uint*)(Bls + c * 512), 16, 0, 0);
        }
        __syncthreads();

        const int fr = ln & 15, kb = (ln >> 4) * 8;
        short8 af[4], bfr[4];
        #pragma unroll
        for (int i = 0; i < 4; i++)
            af[i] = *(const short8*)&Als[(wm * 64 + i * 16 + fr) * 32 + kb];
        #pragma unroll
        for (int j = 0; j < 4; j++)
            bfr[j] = *(const short8*)&Bls[(wn * 64 + j * 16 + fr) * 32 + kb];
        #pragma unroll
        for (int i = 0; i < 4; i++)
            #pragma unroll
            for (int j = 0; j < 4; j++)
                acc[i][j] = __builtin_amdgcn_mfma_f32_16x16x32_bf16(
                    af[i], bfr[j], acc[i][j], 0, 0, 0);
    }

    uint8_t* C8 = (uint8_t*)C;
    const int fr = ln & 15, rq = (ln >> 4) * 4;
    #pragma unroll
    for (int j = 0; j < 4; j++) {
        const int col = n0 + wn * 64 + j * 16 + fr;
        const float bv = bias[col];
        #pragma unroll
        for (int i = 0; i < 4; i++) {
            #pragma unroll
            for (int r = 0; r < 4; r++) {
                const int row = m0 + wm * 64 + i * 16 + rq + r;
                float v = acc[i][j][r] + bv;
                if (relu) v = fmaxf(v, 0.f);
                if (mode == 0) {
                    C[(size_t)row * N + col] = f2bf(v);
                } else {
                    const int bb = (row >= S_) ? 1 : 0;
                    const int loc = row - bb * S_;
                    const int hh = col >> 5, ch = col & 31;
                    const int pk = __builtin_amdgcn_cvt_pk_fp8_f32(v, v, 0, false);
                    C8[((size_t)(bb * 8 + hh) * S_ + loc) * 32 + ch] = (uint8_t)(pk & 0xff);
                }
            }
        }
    }
}

// ---------------------------------------------------------------------------
// Residual + LayerNorm, wave-per-row, vectorized, no LDS/barriers.
// ---------------------------------------------------------------------------
__global__ __launch_bounds__(256) void ln_row(
    const ushort* __restrict__ a16, const ushort* __restrict__ r16,
    const float* __restrict__ g, const float* __restrict__ be,
    float* __restrict__ o32, ushort* __restrict__ o16)
{
    const int wv = threadIdx.x >> 6, ln = threadIdx.x & 63;
    const int row = blockIdx.x * 4 + wv;
    const int col = ln * 4;
    const size_t base = (size_t)row * 256 + col;

    const ushort4 av = *(const ushort4*)(a16 + base);
    const ushort4 rv = *(const ushort4*)(r16 + base);
    float v0 = bf2f(av.x) + bf2f(rv.x);
    float v1 = bf2f(av.y) + bf2f(rv.y);
    float v2 = bf2f(av.z) + bf2f(rv.z);
    float v3 = bf2f(av.w) + bf2f(rv.w);

    float s = v0 + v1 + v2 + v3;
    float s2 = v0 * v0 + v1 * v1 + v2 * v2 + v3 * v3;
    #pragma unroll
    for (int o = 32; o > 0; o >>= 1) {
        s  += __shfl_down(s, o);
        s2 += __shfl_down(s2, o);
    }
    s = __shfl(s, 0);
    s2 = __shfl(s2, 0);
    const float mean = s * (1.f / 256.f);
    const float var = s2 * (1.f / 256.f) - mean * mean;
    const float rstd = rsqrtf(var + EPS_);

    const float4 gv = *(const float4*)(g + col);
    const float4 bv = *(const float4*)(be + col);
    const float o0 = (v0 - mean) * rstd * gv.x + bv.x;
    const float o1 = (v1 - mean) * rstd * gv.y + bv.y;
    const float o2 = (v2 - mean) * rstd * gv.z + bv.z;
    const float o3 = (v3 - mean) * rstd * gv.w + bv.w;

    if (o32) {
        float4 o; o.x = o0; o.y = o1; o.z = o2; o.w = o3;
        *(float4*)(o32 + base) = o;
    } else {
        ushort4 o; o.x = f2bf(o0); o.y = f2bf(o1); o.z = f2bf(o2); o.w = f2bf(o3);
        *(ushort4*)(o16 + base) = o;
    }
}

// ---------------------------------------------------------------------------
// Deformable sampling v7: owner-lane math + sample6's cooperative
// corner-pair region loads. Lane cg of each (q,h) 4-lane group owns level
// cg's 4 samples: computes softmax partials + region {index, wA, wB} once;
// weights packed bf16-pair so broadcast = 2 shuffles/region (DS pipe).
// Load/accumulate pattern identical to sample6 (64B regions, lane reads
// 16B slice at cg*16; half=cg>>1 picks x-corner, final shfl_xor(2) merge).
// ---------------------------------------------------------------------------
__global__ __launch_bounds__(256) void sample7(
    const uint8_t* __restrict__ value, const ushort* __restrict__ offaw,
    const float* __restrict__ refp, ushort* __restrict__ samp)
{
    const int nwg = M_ / 8;                       // 5440 (%8 == 0)
    const int bid = blockIdx.x;
    const int wg = (bid & 7) * (nwg >> 3) + (bid >> 3);

    const int t = threadIdx.x;
    const int q = wg * 8 + (t >> 5);
    const int w = t & 31;
    const int h = w >> 2, cg = w & 3;
    const int half = cg >> 1;
    const int b = q / S_;
    const int gbase = (t & 63) & ~3;              // 4-lane group base in wave

    // own level geometry (level = cg)
    const int Wl = 128 >> cg;
    const float fW = (float)Wl;
    const int st = (cg == 0) ? 0 : (cg == 1) ? 16384 : (cg == 2) ? 20480 : 21504;

    // group softmax: each lane holds its level's 4 logits
    const ushort* awq = offaw + (size_t)q * 384 + 256 + h * 16 + cg * 4;
    const uint2 lg = *(const uint2*)awq;
    const float l0 = bf2f((ushort)(lg.x & 0xffff)), l1 = bf2f((ushort)(lg.x >> 16));
    const float l2 = bf2f((ushort)(lg.y & 0xffff)), l3 = bf2f((ushort)(lg.y >> 16));
    float mx = fmaxf(fmaxf(l0, l1), fmaxf(l2, l3));
    mx = fmaxf(mx, __shfl_xor(mx, 1));
    mx = fmaxf(mx, __shfl_xor(mx, 2));
    const float e0 = __expf(l0 - mx), e1 = __expf(l1 - mx);
    const float e2 = __expf(l2 - mx), e3 = __expf(l3 - mx);
    float sm = e0 + e1 + e2 + e3;
    sm += __shfl_xor(sm, 1);
    sm += __shfl_xor(sm, 2);
    const float inv = 1.f / sm;
    const float aj[4] = {e0 * inv, e1 * inv, e2 * inv, e3 * inv};

    // own 4 samples' offsets + reference point
    const ushort* ofq = offaw + (size_t)q * 384 + h * 32 + cg * 8;
    const uint4 of = *(const uint4*)ofq;
    const uint ou[4] = {of.x, of.y, of.z, of.w};
    const float rx = refp[(size_t)q * 8 + cg * 2];
    const float ry = refp[(size_t)q * 8 + cg * 2 + 1];

    // owner math: 8 regions (4 samples x 2 y-rows)
    int  rxo[8];
    uint wpk[8];                                  // bf16(wA) | bf16(wB)<<16
    #pragma unroll
    for (int j = 0; j < 4; j++) {
        const float ox = bf2f((ushort)(ou[j] & 0xffff));
        const float oy = bf2f((ushort)(ou[j] >> 16));
        const float x = fmaf(rx, fW, ox) - 0.5f;
        const float y = fmaf(ry, fW, oy) - 0.5f;
        const float fx0 = floorf(x), fy0 = floorf(y);
        const float dx = x - fx0, dy = y - fy0;
        const int x0 = (int)fx0, y0 = (int)fy0;

        const int bx = min(max(x0, 0), Wl - 2);
        const float mwx0 = ((x0 >= 0) & (x0 < Wl)) ? (1.f - dx) : 0.f;
        const float mwx1 = ((x0 + 1 >= 0) & (x0 + 1 < Wl)) ? dx : 0.f;
        const int xc0 = min(max(x0, 0), Wl - 1);
        const int xc1 = min(max(x0 + 1, 0), Wl - 1);
        const float wAx = (xc0 == bx ? mwx0 : 0.f) + (xc1 == bx ? mwx1 : 0.f);
        const float wBx = (xc0 == bx + 1 ? mwx0 : 0.f) + (xc1 == bx + 1 ? mwx1 : 0.f);

        const int yc0 = min(max(y0, 0), Wl - 1);
        const int yc1 = min(max(y0 + 1, 0), Wl - 1);
        const float mwy0 = ((y0 >= 0) & (y0 < Wl)) ? (1.f - dy) : 0.f;
        const float mwy1 = ((y0 + 1 >= 0) & (y0 + 1 < Wl)) ? dy : 0.f;

        const float a = aj[j];
        const float wA0 = a * wAx * mwy0, wB0 = a * wBx * mwy0;
        const float wA1 = a * wAx * mwy1, wB1 = a * wBx * mwy1;
        rxo[2 * j]     = (st + yc0 * Wl + bx) * 32;
        rxo[2 * j + 1] = (st + yc1 * Wl + bx) * 32;
        wpk[2 * j]     = (uint)f2bf(wA0) | ((uint)f2bf(wB0) << 16);
        wpk[2 * j + 1] = (uint)f2bf(wA1) | ((uint)f2bf(wB1) << 16);
    }

    // gather all 32 regions: indices/weights broadcast from owner lanes
    const uint8_t* vb = value + (size_t)(b * 8 + h) * S_ * 32 + cg * 16;
    f32x2 acc[8];
    #pragma unroll
    for (int k = 0; k < 8; k++) acc[k] = (f32x2){0.f, 0.f};

    #pragma unroll
    for (int ol = 0; ol < 4; ol++) {
        const int srcl = gbase + ol;
        #pragma unroll
        for (int r = 0; r < 8; r++) {
            const int  rix = __shfl(rxo[r], srcl, 64);
            const uint wp  = (uint)__shfl((int)wpk[r], srcl, 64);
            const float wv = bf2f((ushort)(half ? (wp >> 16) : (wp & 0xffffu)));
            const uint4 u = *(const uint4*)(vb + rix);
            const f32x2 w2 = {wv, wv};
            acc[0] += w2 * __builtin_amdgcn_cvt_pk_f32_fp8((int)u.x, false);
            acc[1] += w2 * __builtin_amdgcn_cvt_pk_f32_fp8((int)u.x, true);
            acc[2] += w2 * __builtin_amdgcn_cvt_pk_f32_fp8((int)u.y, false);
            acc[3] += w2 * __builtin_amdgcn_cvt_pk_f32_fp8((int)u.y, true);
            acc[4] += w2 * __builtin_amdgcn_cvt_pk_f32_fp8((int)u.z, false);
            acc[5] += w2 * __builtin_amdgcn_cvt_pk_f32_fp8((int)u.z, true);
            acc[6] += w2 * __builtin_amdgcn_cvt_pk_f32_fp8((int)u.w, false);
            acc[7] += w2 * __builtin_amdgcn_cvt_pk_f32_fp8((int)u.w, true);
        }
    }

    // combine the two x-halves (lanes cg and cg^2 hold same 16 channels)
    #pragma unroll
    for (int k = 0; k < 8; k++) {
        acc[k].x += __shfl_xor(acc[k].x, 2);
        acc[k].y += __shfl_xor(acc[k].y, 2);
    }

    f32x2 r0, r1, r2, r3;
    if (half == 0) { r0 = acc[0]; r1 = acc[1]; r2 = acc[2]; r3 = acc[3]; }
    else           { r0 = acc[4]; r1 = acc[5]; r2 = acc[6]; r3 = acc[7]; }

    const int ch_start = (cg & 1) * 16 + half * 8;
    uint4 o;
    o.x = (uint)f2bf(r0.x) | ((uint)f2bf(r0.y) << 16);
    o.y = (uint)f2bf(r1.x) | ((uint)f2bf(r1.y) << 16);
    o.z = (uint)f2bf(r2.x) | ((uint)f2bf(r2.y) << 16);
    o.w = (uint)f2bf(r3.x) | ((uint)f2bf(r3.y) << 16);
    *(uint4*)(samp + (size_t)q * 256 + h * 32 + ch_start) = o;
}

// ---------------------------------------------------------------------------
extern "C" void kernel_launch(void* const* d_in, const int* in_sizes, int n_in,
                              void* d_out, int out_size, void* d_ws, size_t ws_size,
                              hipStream_t stream)
{
    const float* src    = (const float*)d_in[0];
    const float* pos    = (const float*)d_in[1];
    const float* refp   = (const float*)d_in[2];
    const float* W_off  = (const float*)d_in[5];
    const float* b_off  = (const float*)d_in[6];
    const float* W_attn = (const float*)d_in[7];
    const float* b_attn = (const float*)d_in[8];
    const float* W_val  = (const float*)d_in[9];
    const float* b_val  = (const float*)d_in[10];
    const float* W_out  = (const float*)d_in[11];
    const float* b_out  = (const float*)d_in[12];
    const float* g1     = (const float*)d_in[13];
    const float* be1    = (const float*)d_in[14];
    const float* W_ff1  = (const float*)d_in[15];
    const float* b_ff1  = (const float*)d_in[16];
    const float* W_ff2  = (const float*)d_in[17];
    const float* b_ff2  = (const float*)d_in[18];
    const float* g2     = (const float*)d_in[19];
    const float* be2    = (const float*)d_in[20];
    float* out = (float*)d_out;

    const size_t szMDh = (size_t)M_ * 256 * 2;      // 22,282,240 B
    const size_t szOAh = (size_t)M_ * 384 * 2;      // 33,423,360 B

    char* ws = (char*)d_ws;
    ushort* WT      = (ushort*)ws;
    ushort* WT_val  = WT;
    ushort* WT_oa   = WT + 65536;
    ushort* WT_out  = WT + 163840;
    ushort* WT_ff1  = WT + 229376;
    ushort* WT_ff2  = WT + 491520;
    float*  bias_oa = (float*)(ws + 1507328);

    const size_t o_src  = 2097152;
    const size_t o_q    = o_src + szMDh;
    const size_t o_val  = o_q   + szMDh;
    const size_t o_oa   = o_val + szMDh;
    const size_t o_x    = o_oa  + szOAh;
    const size_t o_ffn  = o_x   + szMDh;            // total 146.9 MB (proven fit)

    ushort* src_bf  = (ushort*)(ws + o_src);
    ushort* q_bf    = (ushort*)(ws + o_q);
    ushort* val_f8  = (ushort*)(ws + o_val);
    ushort* offaw   = (ushort*)(ws + o_oa);
    ushort* x_bf    = (ushort*)(ws + o_x);
    ushort* ffn_bf  = (ushort*)(ws + o_ffn);
    ushort* samp_bf = q_bf;      // q_bf dead after offaw GEMM
    ushort* attn_bf = val_f8;    // val dead after sampling
    ushort* hbuf    = src_bf;    // src..oa free after ln1 (100.3 MB >= 89.1)

    // 0) converts (src/q) + all weight transposes, one dispatch
    prep_all<<<CVT_BLOCKS + 2947, 256, 0, stream>>>(
        src, pos, src_bf, q_bf,
        W_val, W_off, W_attn, W_out, W_ff1, W_ff2, b_off, b_attn, WT, bias_oa);
    // 1) value = src @ W_val + b_val  (fp8 head-major)
    mgemm<<<2 * (M_ / 128), 256, 0, stream>>>(src_bf, WT_val, b_val, val_f8, M_, 256, 256, 0, 2);
    // 2) offaw = (src+pos) @ [W_off|W_attn] + bias
    mgemm<<<3 * (M_ / 128), 256, 0, stream>>>(q_bf, WT_oa, bias_oa, offaw, M_, 384, 256, 0, 0);
    // 3) sampling (owner-lane math)
    sample7<<<M_ / 8, 256, 0, stream>>>((const uint8_t*)val_f8, offaw, refp, samp_bf);
    // 4) attn_out = samp @ W_out + b_out
    mgemm<<<2 * (M_ / 128), 256, 0, stream>>>(samp_bf, WT_out, b_out, attn_bf, M_, 256, 256, 0, 0);
    // 5) x = LN(src_bf + attn)
    ln_row<<<M_ / 4, 256, 0, stream>>>(attn_bf, src_bf, g1, be1, nullptr, x_bf);
    // 6) FFN1: h = relu(x @ W_ff1 + b_ff1)
    mgemm<<<8 * (M_ / 128), 256, 0, stream>>>(x_bf, WT_ff1, b_ff1, hbuf, M_, DFF_, 256, 1, 0);
    // 7) FFN2: ffn = h @ W_ff2 + b_ff2
    mgemm<<<2 * (M_ / 128), 256, 0, stream>>>(hbuf, WT_ff2, b_ff2, ffn_bf, M_, 256, DFF_, 0, 0);
    // 8) out = LN(x + ffn)
    ln_row<<<M_ / 4, 256, 0, stream>>>(ffn_bf, x_bf, g2, be2, out, nullptr);
}

// Round 12
// 263.585 us; speedup vs baseline: 1.2743x; 1.0331x over previous
//
#include <hip/hip_runtime.h>
#include <cstdint>
#include <cstddef>

#define B_   2
#define S_   21760
#define M_   (B_ * S_)     // 43520
#define D_   256
#define DFF_ 1024
#define EPS_ 1e-5f

typedef __attribute__((ext_vector_type(8))) short short8;
typedef __attribute__((ext_vector_type(4))) float f32x4;
typedef __attribute__((ext_vector_type(2))) float f32x2;

__device__ __forceinline__ ushort f2bf(float f) {
    uint x = __float_as_uint(f);
    return (ushort)((x + 0x7fffu + ((x >> 16) & 1u)) >> 16);
}
__device__ __forceinline__ float bf2f(ushort u) {
    return __uint_as_float(((uint)u) << 16);
}

// ---------------------------------------------------------------------------
// Merged prep: blocks [0,10880) do src/q bf16 converts; rest do weight
// transpose+convert + bias concat (one dispatch total).
// ---------------------------------------------------------------------------
#define CVT_BLOCKS 10880
__global__ __launch_bounds__(256) void prep_all(
    const float* __restrict__ src, const float* __restrict__ pos,
    ushort* __restrict__ sb, ushort* __restrict__ qb,
    const float* __restrict__ Wval, const float* __restrict__ Woff,
    const float* __restrict__ Wattn, const float* __restrict__ Wout,
    const float* __restrict__ Wff1, const float* __restrict__ Wff2,
    const float* __restrict__ boff, const float* __restrict__ battn,
    ushort* __restrict__ WT, float* __restrict__ bias_oa)
{
    if (blockIdx.x < CVT_BLOCKS) {
        const size_t i = ((size_t)blockIdx.x * 256 + threadIdx.x) * 4;
        const float4 s = *(const float4*)(src + i);
        const float4 p = *(const float4*)(pos + i);
        ushort4 so, qo;
        so.x = f2bf(s.x); so.y = f2bf(s.y); so.z = f2bf(s.z); so.w = f2bf(s.w);
        qo.x = f2bf(s.x + p.x); qo.y = f2bf(s.y + p.y);
        qo.z = f2bf(s.z + p.z); qo.w = f2bf(s.w + p.w);
        *(ushort4*)(sb + i) = so;
        *(ushort4*)(qb + i) = qo;
        return;
    }
    const int i = (blockIdx.x - CVT_BLOCKS) * 256 + threadIdx.x;
    if (i < 65536) {
        const int n = i >> 8, k = i & 255;
        WT[i] = f2bf(Wval[(size_t)k * 256 + n]);
    } else if (i < 163840) {
        const int j = i - 65536;
        const int n = j >> 8, k = j & 255;
        WT[i] = (n < 256) ? f2bf(Woff[(size_t)k * 256 + n])
                          : f2bf(Wattn[(size_t)k * 128 + (n - 256)]);
    } else if (i < 229376) {
        const int j = i - 163840;
        const int n = j >> 8, k = j & 255;
        WT[i] = f2bf(Wout[(size_t)k * 256 + n]);
    } else if (i < 491520) {
        const int j = i - 229376;
        const int n = j >> 8, k = j & 255;
        WT[i] = f2bf(Wff1[(size_t)k * 1024 + n]);
    } else if (i < 753664) {
        const int j = i - 491520;
        const int n = j >> 10, k = j & 1023;
        WT[i] = f2bf(Wff2[(size_t)k * 256 + n]);
    } else if (i < 753664 + 384) {
        const int j = i - 753664;
        bias_oa[j] = (j < 256) ? boff[j] : battn[j - 256];
    }
}

// ---------------------------------------------------------------------------
// bf16 MFMA GEMM: 128x128 tile, BK=32, 4 waves, 4x4 16x16x32 fragments.
// 1D grid with bijective XCD-chunked swizzle. mode 0: bf16 row-major.
// mode 2: fp8 e4m3 head-major value layout.
// ---------------------------------------------------------------------------
__global__ __launch_bounds__(256) void mgemm(
    const ushort* __restrict__ A, const ushort* __restrict__ WT,
    const float* __restrict__ bias, ushort* __restrict__ C,
    int M, int N, int K, int relu, int mode)
{
    __shared__ __align__(16) ushort Als[128 * 32];
    __shared__ __align__(16) ushort Bls[128 * 32];

    const int nwg = gridDim.x;
    const int bid = blockIdx.x;
    const int q8 = nwg >> 3, r8 = nwg & 7;
    const int xcd = bid & 7, blk = bid >> 3;
    const int wg = (xcd < r8 ? xcd * (q8 + 1) : r8 * (q8 + 1) + (xcd - r8) * q8) + blk;
    const int gx = N >> 7;
    const int n0 = (wg % gx) << 7;
    const int m0 = (wg / gx) << 7;

    const int tid = threadIdx.x;
    const int wv = tid >> 6, ln = tid & 63;
    const int wm = wv >> 1, wn = wv & 1;

    const int lrow = ln >> 2, lcol = (ln & 3) * 8;

    f32x4 acc[4][4];
    const f32x4 zz = {0.f, 0.f, 0.f, 0.f};
    #pragma unroll
    for (int i = 0; i < 4; i++)
        #pragma unroll
        for (int j = 0; j < 4; j++) acc[i][j] = zz;

    for (int k0 = 0; k0 < K; k0 += 32) {
        __syncthreads();
        #pragma unroll
        for (int r = 0; r < 2; ++r) {
            const int c = r * 4 + wv;
            const ushort* ga = A + (size_t)(m0 + c * 16 + lrow) * K + k0 + lcol;
            __builtin_amdgcn_global_load_lds(
                (const __attribute__((address_space(1))) uint*)ga,
                (__attribute__((address_space(3))) uint*)(Als + c * 512), 16, 0, 0);
            const ushort* gb = WT + (size_t)(n0 + c * 16 + lrow) * K + k0 + lcol;
            __builtin_amdgcn_global_load_lds(
                (const __attribute__((address_space(1))) uint*)gb,
                (__attribute__((address_space(3))) uint*)(Bls + c * 512), 16, 0, 0);
        }
        __syncthreads();

        const int fr = ln & 15, kb = (ln >> 4) * 8;
        short8 af[4], bfr[4];
        #pragma unroll
        for (int i = 0; i < 4; i++)
            af[i] = *(const short8*)&Als[(wm * 64 + i * 16 + fr) * 32 + kb];
        #pragma unroll
        for (int j = 0; j < 4; j++)
            bfr[j] = *(const short8*)&Bls[(wn * 64 + j * 16 + fr) * 32 + kb];
        #pragma unroll
        for (int i = 0; i < 4; i++)
            #pragma unroll
            for (int j = 0; j < 4; j++)
                acc[i][j] = __builtin_amdgcn_mfma_f32_16x16x32_bf16(
                    af[i], bfr[j], acc[i][j], 0, 0, 0);
    }

    uint8_t* C8 = (uint8_t*)C;
    const int fr = ln & 15, rq = (ln >> 4) * 4;
    #pragma unroll
    for (int j = 0; j < 4; j++) {
        const int col = n0 + wn * 64 + j * 16 + fr;
        const float bv = bias[col];
        #pragma unroll
        for (int i = 0; i < 4; i++) {
            #pragma unroll
            for (int r = 0; r < 4; r++) {
                const int row = m0 + wm * 64 + i * 16 + rq + r;
                float v = acc[i][j][r] + bv;
                if (relu) v = fmaxf(v, 0.f);
                if (mode == 0) {
                    C[(size_t)row * N + col] = f2bf(v);
                } else {
                    const int bb = (row >= S_) ? 1 : 0;
                    const int loc = row - bb * S_;
                    const int hh = col >> 5, ch = col & 31;
                    const int pk = __builtin_amdgcn_cvt_pk_fp8_f32(v, v, 0, false);
                    C8[((size_t)(bb * 8 + hh) * S_ + loc) * 32 + ch] = (uint8_t)(pk & 0xff);
                }
            }
        }
    }
}

// ---------------------------------------------------------------------------
// Residual + LayerNorm, wave-per-row, vectorized, no LDS/barriers.
// ---------------------------------------------------------------------------
__global__ __launch_bounds__(256) void ln_row(
    const ushort* __restrict__ a16, const ushort* __restrict__ r16,
    const float* __restrict__ g, const float* __restrict__ be,
    float* __restrict__ o32, ushort* __restrict__ o16)
{
    const int wv = threadIdx.x >> 6, ln = threadIdx.x & 63;
    const int row = blockIdx.x * 4 + wv;
    const int col = ln * 4;
    const size_t base = (size_t)row * 256 + col;

    const ushort4 av = *(const ushort4*)(a16 + base);
    const ushort4 rv = *(const ushort4*)(r16 + base);
    float v0 = bf2f(av.x) + bf2f(rv.x);
    float v1 = bf2f(av.y) + bf2f(rv.y);
    float v2 = bf2f(av.z) + bf2f(rv.z);
    float v3 = bf2f(av.w) + bf2f(rv.w);

    float s = v0 + v1 + v2 + v3;
    float s2 = v0 * v0 + v1 * v1 + v2 * v2 + v3 * v3;
    #pragma unroll
    for (int o = 32; o > 0; o >>= 1) {
        s  += __shfl_down(s, o);
        s2 += __shfl_down(s2, o);
    }
    s = __shfl(s, 0);
    s2 = __shfl(s2, 0);
    const float mean = s * (1.f / 256.f);
    const float var = s2 * (1.f / 256.f) - mean * mean;
    const float rstd = rsqrtf(var + EPS_);

    const float4 gv = *(const float4*)(g + col);
    const float4 bv = *(const float4*)(be + col);
    const float o0 = (v0 - mean) * rstd * gv.x + bv.x;
    const float o1 = (v1 - mean) * rstd * gv.y + bv.y;
    const float o2 = (v2 - mean) * rstd * gv.z + bv.z;
    const float o3 = (v3 - mean) * rstd * gv.w + bv.w;

    if (o32) {
        float4 o; o.x = o0; o.y = o1; o.z = o2; o.w = o3;
        *(float4*)(o32 + base) = o;
    } else {
        ushort4 o; o.x = f2bf(o0); o.y = f2bf(o1); o.z = f2bf(o2); o.w = f2bf(o3);
        *(ushort4*)(o16 + base) = o;
    }
}

// ---------------------------------------------------------------------------
// Deformable sampling v8: (b,h)-partitioned blocks for L2-resident gathers.
// Block = 64 queries x 4 lanes, ONE (b,h) per block; 16 bh-slices x 340
// q-chunks = 5440 blocks; XCD-chunked so XCD x owns bh {2x, 2x+1} ->
// per-XCD value working set 2 x 680 KB = 1.36 MB << 4 MB L2.
// Group math identical to sample7 (owner-lane, corner-pair region loads).
// ---------------------------------------------------------------------------
__global__ __launch_bounds__(256) void sample8(
    const uint8_t* __restrict__ value, const ushort* __restrict__ offaw,
    const float* __restrict__ refp, ushort* __restrict__ samp)
{
    // XCD-chunk: 5440 blocks, 680 per XCD -> XCD x owns wg [x*680,(x+1)*680)
    const int bid = blockIdx.x;
    const int wg = (bid & 7) * 680 + (bid >> 3);
    const int bh = wg / 340;                      // 0..15
    const int qc = wg - bh * 340;                 // q-chunk
    const int b = bh >> 3, h = bh & 7;

    const int tid = threadIdx.x;
    const int g = tid >> 2, cg = tid & 3;
    const int q = b * S_ + qc * 64 + g;           // global row in [0,M)
    const int half = cg >> 1;
    const int gbase = (tid & 63) & ~3;

    // own level geometry (level = cg)
    const int Wl = 128 >> cg;
    const float fW = (float)Wl;
    const int st = (cg == 0) ? 0 : (cg == 1) ? 16384 : (cg == 2) ? 20480 : 21504;

    // group softmax: lane cg holds level cg's 4 logits
    const ushort* awq = offaw + (size_t)q * 384 + 256 + h * 16 + cg * 4;
    const uint2 lg = *(const uint2*)awq;
    const float l0 = bf2f((ushort)(lg.x & 0xffff)), l1 = bf2f((ushort)(lg.x >> 16));
    const float l2 = bf2f((ushort)(lg.y & 0xffff)), l3 = bf2f((ushort)(lg.y >> 16));
    float mx = fmaxf(fmaxf(l0, l1), fmaxf(l2, l3));
    mx = fmaxf(mx, __shfl_xor(mx, 1));
    mx = fmaxf(mx, __shfl_xor(mx, 2));
    const float e0 = __expf(l0 - mx), e1 = __expf(l1 - mx);
    const float e2 = __expf(l2 - mx), e3 = __expf(l3 - mx);
    float sm = e0 + e1 + e2 + e3;
    sm += __shfl_xor(sm, 1);
    sm += __shfl_xor(sm, 2);
    const float inv = 1.f / sm;
    const float aj[4] = {e0 * inv, e1 * inv, e2 * inv, e3 * inv};

    // own 4 samples' offsets + reference point
    const ushort* ofq = offaw + (size_t)q * 384 + h * 32 + cg * 8;
    const uint4 of = *(const uint4*)ofq;
    const uint ou[4] = {of.x, of.y, of.z, of.w};
    const float rx = refp[(size_t)q * 8 + cg * 2];
    const float ry = refp[(size_t)q * 8 + cg * 2 + 1];

    // owner math: 8 regions (4 samples x 2 y-rows)
    int  rxo[8];
    uint wpk[8];                                  // bf16(wA) | bf16(wB)<<16
    #pragma unroll
    for (int j = 0; j < 4; j++) {
        const float ox = bf2f((ushort)(ou[j] & 0xffff));
        const float oy = bf2f((ushort)(ou[j] >> 16));
        const float x = fmaf(rx, fW, ox) - 0.5f;
        const float y = fmaf(ry, fW, oy) - 0.5f;
        const float fx0 = floorf(x), fy0 = floorf(y);
        const float dx = x - fx0, dy = y - fy0;
        const int x0 = (int)fx0, y0 = (int)fy0;

        const int bx = min(max(x0, 0), Wl - 2);
        const float mwx0 = ((x0 >= 0) & (x0 < Wl)) ? (1.f - dx) : 0.f;
        const float mwx1 = ((x0 + 1 >= 0) & (x0 + 1 < Wl)) ? dx : 0.f;
        const int xc0 = min(max(x0, 0), Wl - 1);
        const int xc1 = min(max(x0 + 1, 0), Wl - 1);
        const float wAx = (xc0 == bx ? mwx0 : 0.f) + (xc1 == bx ? mwx1 : 0.f);
        const float wBx = (xc0 == bx + 1 ? mwx0 : 0.f) + (xc1 == bx + 1 ? mwx1 : 0.f);

        const int yc0 = min(max(y0, 0), Wl - 1);
        const int yc1 = min(max(y0 + 1, 0), Wl - 1);
        const float mwy0 = ((y0 >= 0) & (y0 < Wl)) ? (1.f - dy) : 0.f;
        const float mwy1 = ((y0 + 1 >= 0) & (y0 + 1 < Wl)) ? dy : 0.f;

        const float a = aj[j];
        rxo[2 * j]     = (st + yc0 * Wl + bx) * 32;
        rxo[2 * j + 1] = (st + yc1 * Wl + bx) * 32;
        wpk[2 * j]     = (uint)f2bf(a * wAx * mwy0) | ((uint)f2bf(a * wBx * mwy0) << 16);
        wpk[2 * j + 1] = (uint)f2bf(a * wAx * mwy1) | ((uint)f2bf(a * wBx * mwy1) << 16);
    }

    // gather all 32 regions (L2-resident per XCD)
    const uint8_t* vb = value + (size_t)(b * 8 + h) * S_ * 32 + cg * 16;
    f32x2 acc[8];
    #pragma unroll
    for (int k = 0; k < 8; k++) acc[k] = (f32x2){0.f, 0.f};

    #pragma unroll
    for (int ol = 0; ol < 4; ol++) {
        const int srcl = gbase + ol;
        #pragma unroll
        for (int r = 0; r < 8; r++) {
            const int  rix = __shfl(rxo[r], srcl, 64);
            const uint wp  = (uint)__shfl((int)wpk[r], srcl, 64);
            const float wv = bf2f((ushort)(half ? (wp >> 16) : (wp & 0xffffu)));
            const uint4 u = *(const uint4*)(vb + rix);
            const f32x2 w2 = {wv, wv};
            acc[0] += w2 * __builtin_amdgcn_cvt_pk_f32_fp8((int)u.x, false);
            acc[1] += w2 * __builtin_amdgcn_cvt_pk_f32_fp8((int)u.x, true);
            acc[2] += w2 * __builtin_amdgcn_cvt_pk_f32_fp8((int)u.y, false);
            acc[3] += w2 * __builtin_amdgcn_cvt_pk_f32_fp8((int)u.y, true);
            acc[4] += w2 * __builtin_amdgcn_cvt_pk_f32_fp8((int)u.z, false);
            acc[5] += w2 * __builtin_amdgcn_cvt_pk_f32_fp8((int)u.z, true);
            acc[6] += w2 * __builtin_amdgcn_cvt_pk_f32_fp8((int)u.w, false);
            acc[7] += w2 * __builtin_amdgcn_cvt_pk_f32_fp8((int)u.w, true);
        }
    }

    // combine the two x-halves (lanes cg and cg^2 hold same 16 channels)
    #pragma unroll
    for (int k = 0; k < 8; k++) {
        acc[k].x += __shfl_xor(acc[k].x, 2);
        acc[k].y += __shfl_xor(acc[k].y, 2);
    }

    f32x2 r0, r1, r2, r3;
    if (half == 0) { r0 = acc[0]; r1 = acc[1]; r2 = acc[2]; r3 = acc[3]; }
    else           { r0 = acc[4]; r1 = acc[5]; r2 = acc[6]; r3 = acc[7]; }

    const int ch_start = (cg & 1) * 16 + half * 8;
    uint4 o;
    o.x = (uint)f2bf(r0.x) | ((uint)f2bf(r0.y) << 16);
    o.y = (uint)f2bf(r1.x) | ((uint)f2bf(r1.y) << 16);
    o.z = (uint)f2bf(r2.x) | ((uint)f2bf(r2.y) << 16);
    o.w = (uint)f2bf(r3.x) | ((uint)f2bf(r3.y) << 16);
    *(uint4*)(samp + (size_t)q * 256 + h * 32 + ch_start) = o;
}

// ---------------------------------------------------------------------------
extern "C" void kernel_launch(void* const* d_in, const int* in_sizes, int n_in,
                              void* d_out, int out_size, void* d_ws, size_t ws_size,
                              hipStream_t stream)
{
    const float* src    = (const float*)d_in[0];
    const float* pos    = (const float*)d_in[1];
    const float* refp   = (const float*)d_in[2];
    const float* W_off  = (const float*)d_in[5];
    const float* b_off  = (const float*)d_in[6];
    const float* W_attn = (const float*)d_in[7];
    const float* b_attn = (const float*)d_in[8];
    const float* W_val  = (const float*)d_in[9];
    const float* b_val  = (const float*)d_in[10];
    const float* W_out  = (const float*)d_in[11];
    const float* b_out  = (const float*)d_in[12];
    const float* g1     = (const float*)d_in[13];
    const float* be1    = (const float*)d_in[14];
    const float* W_ff1  = (const float*)d_in[15];
    const float* b_ff1  = (const float*)d_in[16];
    const float* W_ff2  = (const float*)d_in[17];
    const float* b_ff2  = (const float*)d_in[18];
    const float* g2     = (const float*)d_in[19];
    const float* be2    = (const float*)d_in[20];
    float* out = (float*)d_out;

    const size_t szMDh = (size_t)M_ * 256 * 2;      // 22,282,240 B
    const size_t szOAh = (size_t)M_ * 384 * 2;      // 33,423,360 B

    char* ws = (char*)d_ws;
    ushort* WT      = (ushort*)ws;
    ushort* WT_val  = WT;
    ushort* WT_oa   = WT + 65536;
    ushort* WT_out  = WT + 163840;
    ushort* WT_ff1  = WT + 229376;
    ushort* WT_ff2  = WT + 491520;
    float*  bias_oa = (float*)(ws + 1507328);

    const size_t o_src  = 2097152;
    const size_t o_q    = o_src + szMDh;
    const size_t o_val  = o_q   + szMDh;
    const size_t o_oa   = o_val + szMDh;
    const size_t o_x    = o_oa  + szOAh;
    const size_t o_ffn  = o_x   + szMDh;            // total 146.9 MB (proven fit)

    ushort* src_bf  = (ushort*)(ws + o_src);
    ushort* q_bf    = (ushort*)(ws + o_q);
    ushort* val_f8  = (ushort*)(ws + o_val);
    ushort* offaw   = (ushort*)(ws + o_oa);
    ushort* x_bf    = (ushort*)(ws + o_x);
    ushort* ffn_bf  = (ushort*)(ws + o_ffn);
    ushort* samp_bf = q_bf;      // q_bf dead after offaw GEMM
    ushort* attn_bf = val_f8;    // val dead after sampling
    ushort* hbuf    = src_bf;    // src..oa free after ln1 (100.3 MB >= 89.1)

    // 0) converts (src/q) + all weight transposes, one dispatch
    prep_all<<<CVT_BLOCKS + 2947, 256, 0, stream>>>(
        src, pos, src_bf, q_bf,
        W_val, W_off, W_attn, W_out, W_ff1, W_ff2, b_off, b_attn, WT, bias_oa);
    // 1) value = src @ W_val + b_val  (fp8 head-major)
    mgemm<<<2 * (M_ / 128), 256, 0, stream>>>(src_bf, WT_val, b_val, val_f8, M_, 256, 256, 0, 2);
    // 2) offaw = (src+pos) @ [W_off|W_attn] + bias
    mgemm<<<3 * (M_ / 128), 256, 0, stream>>>(q_bf, WT_oa, bias_oa, offaw, M_, 384, 256, 0, 0);
    // 3) sampling ((b,h)-partitioned, L2-resident)
    sample8<<<16 * 340, 256, 0, stream>>>((const uint8_t*)val_f8, offaw, refp, samp_bf);
    // 4) attn_out = samp @ W_out + b_out
    mgemm<<<2 * (M_ / 128), 256, 0, stream>>>(samp_bf, WT_out, b_out, attn_bf, M_, 256, 256, 0, 0);
    // 5) x = LN(src_bf + attn)
    ln_row<<<M_ / 4, 256, 0, stream>>>(attn_bf, src_bf, g1, be1, nullptr, x_bf);
    // 6) FFN1: h = relu(x @ W_ff1 + b_ff1)
    mgemm<<<8 * (M_ / 128), 256, 0, stream>>>(x_bf, WT_ff1, b_ff1, hbuf, M_, DFF_, 256, 1, 0);
    // 7) FFN2: ffn = h @ W_ff2 + b_ff2
    mgemm<<<2 * (M_ / 128), 256, 0, stream>>>(hbuf, WT_ff2, b_ff2, ffn_bf, M_, 256, DFF_, 0, 0);
    // 8) out = LN(x + ffn)
    ln_row<<<M_ / 4, 256, 0, stream>>>(ffn_bf, x_bf, g2, be2, out, nullptr);
}

// Round 13
// 249.609 us; speedup vs baseline: 1.3456x; 1.0560x over previous
//
#include <hip/hip_runtime.h>
#include <cstdint>
#include <cstddef>

#define B_   2
#define S_   21760
#define M_   (B_ * S_)     // 43520
#define D_   256
#define DFF_ 1024
#define EPS_ 1e-5f

typedef __attribute__((ext_vector_type(8))) short short8;
typedef __attribute__((ext_vector_type(4))) float f32x4;
typedef __attribute__((ext_vector_type(2))) float f32x2;

__device__ __forceinline__ ushort f2bf(float f) {
    uint x = __float_as_uint(f);
    return (ushort)((x + 0x7fffu + ((x >> 16) & 1u)) >> 16);
}
__device__ __forceinline__ float bf2f(ushort u) {
    return __uint_as_float(((uint)u) << 16);
}

// ---------------------------------------------------------------------------
// Merged prep: blocks [0,10880) do src/q bf16 converts; rest do weight
// transpose+convert + bias concat (one dispatch total).
// ---------------------------------------------------------------------------
#define CVT_BLOCKS 10880
__global__ __launch_bounds__(256) void prep_all(
    const float* __restrict__ src, const float* __restrict__ pos,
    ushort* __restrict__ sb, ushort* __restrict__ qb,
    const float* __restrict__ Wval, const float* __restrict__ Woff,
    const float* __restrict__ Wattn, const float* __restrict__ Wout,
    const float* __restrict__ Wff1, const float* __restrict__ Wff2,
    const float* __restrict__ boff, const float* __restrict__ battn,
    ushort* __restrict__ WT, float* __restrict__ bias_oa)
{
    if (blockIdx.x < CVT_BLOCKS) {
        const size_t i = ((size_t)blockIdx.x * 256 + threadIdx.x) * 4;
        const float4 s = *(const float4*)(src + i);
        const float4 p = *(const float4*)(pos + i);
        ushort4 so, qo;
        so.x = f2bf(s.x); so.y = f2bf(s.y); so.z = f2bf(s.z); so.w = f2bf(s.w);
        qo.x = f2bf(s.x + p.x); qo.y = f2bf(s.y + p.y);
        qo.z = f2bf(s.z + p.z); qo.w = f2bf(s.w + p.w);
        *(ushort4*)(sb + i) = so;
        *(ushort4*)(qb + i) = qo;
        return;
    }
    const int i = (blockIdx.x - CVT_BLOCKS) * 256 + threadIdx.x;
    if (i < 65536) {
        const int n = i >> 8, k = i & 255;
        WT[i] = f2bf(Wval[(size_t)k * 256 + n]);
    } else if (i < 163840) {
        const int j = i - 65536;
        const int n = j >> 8, k = j & 255;
        WT[i] = (n < 256) ? f2bf(Woff[(size_t)k * 256 + n])
                          : f2bf(Wattn[(size_t)k * 128 + (n - 256)]);
    } else if (i < 229376) {
        const int j = i - 163840;
        const int n = j >> 8, k = j & 255;
        WT[i] = f2bf(Wout[(size_t)k * 256 + n]);
    } else if (i < 491520) {
        const int j = i - 229376;
        const int n = j >> 8, k = j & 255;
        WT[i] = f2bf(Wff1[(size_t)k * 1024 + n]);
    } else if (i < 753664) {
        const int j = i - 491520;
        const int n = j >> 10, k = j & 1023;
        WT[i] = f2bf(Wff2[(size_t)k * 256 + n]);
    } else if (i < 753664 + 384) {
        const int j = i - 753664;
        bias_oa[j] = (j < 256) ? boff[j] : battn[j - 256];
    }
}

// ---------------------------------------------------------------------------
// bf16 MFMA GEMM v2: 128x128 tile, BK=64 (half the barriers of BK=32),
// 4 waves, 2x(4x4) 16x16x32 fragments per K-step. LDS [128][64] with
// XOR swizzle (colbyte ^= (row&7)<<4) applied BOTH sides per rule #21:
// linear LDS dest + pre-swizzled GLOBAL source col ((ln&7)^(ln>>3))*8,
// and the matching XOR on ds_read addresses -> conflict-free b128 reads.
// 1D grid, bijective XCD-chunked swizzle. mode 0: bf16 row-major C.
// mode 2: fp8 e4m3 head-major value layout.
// ---------------------------------------------------------------------------
__global__ __launch_bounds__(256) void mgemm(
    const ushort* __restrict__ A, const ushort* __restrict__ WT,
    const float* __restrict__ bias, ushort* __restrict__ C,
    int M, int N, int K, int relu, int mode)
{
    __shared__ __align__(16) ushort Als[128 * 64];
    __shared__ __align__(16) ushort Bls[128 * 64];

    const int nwg = gridDim.x;
    const int bid = blockIdx.x;
    const int q8 = nwg >> 3, r8 = nwg & 7;
    const int xcd = bid & 7, blk = bid >> 3;
    const int wg = (xcd < r8 ? xcd * (q8 + 1) : r8 * (q8 + 1) + (xcd - r8) * q8) + blk;
    const int gx = N >> 7;
    const int n0 = (wg % gx) << 7;
    const int m0 = (wg / gx) << 7;

    const int tid = threadIdx.x;
    const int wv = tid >> 6, ln = tid & 63;
    const int wm = wv >> 1, wn = wv & 1;

    // staging: chunk c covers rows [c*8, c*8+8); lane ln -> row c*8+(ln>>3),
    // global col pre-swizzled so linear LDS matches the read-side XOR.
    const int srow = ln >> 3;
    const int scol = ((ln & 7) ^ srow) * 8;

    f32x4 acc[4][4];
    const f32x4 zz = {0.f, 0.f, 0.f, 0.f};
    #pragma unroll
    for (int i = 0; i < 4; i++)
        #pragma unroll
        for (int j = 0; j < 4; j++) acc[i][j] = zz;

    const int fr = ln & 15, qq = ln >> 4;

    for (int k0 = 0; k0 < K; k0 += 64) {
        __syncthreads();
        #pragma unroll
        for (int r = 0; r < 4; ++r) {
            const int c = r * 4 + wv;
            const ushort* ga = A + (size_t)(m0 + c * 8 + srow) * K + k0 + scol;
            __builtin_amdgcn_global_load_lds(
                (const __attribute__((address_space(1))) uint*)ga,
                (__attribute__((address_space(3))) uint*)(Als + c * 512), 16, 0, 0);
            const ushort* gb = WT + (size_t)(n0 + c * 8 + srow) * K + k0 + scol;
            __builtin_amdgcn_global_load_lds(
                (const __attribute__((address_space(1))) uint*)gb,
                (__attribute__((address_space(3))) uint*)(Bls + c * 512), 16, 0, 0);
        }
        __syncthreads();

        #pragma unroll
        for (int kk = 0; kk < 2; kk++) {
            short8 af[4], bfr[4];
            #pragma unroll
            for (int i = 0; i < 4; i++) {
                const int row = wm * 64 + i * 16 + fr;
                af[i] = *(const short8*)&Als[row * 64 + (((kk * 4 + qq) ^ (row & 7)) * 8)];
            }
            #pragma unroll
            for (int j = 0; j < 4; j++) {
                const int row = wn * 64 + j * 16 + fr;
                bfr[j] = *(const short8*)&Bls[row * 64 + (((kk * 4 + qq) ^ (row & 7)) * 8)];
            }
            #pragma unroll
            for (int i = 0; i < 4; i++)
                #pragma unroll
                for (int j = 0; j < 4; j++)
                    acc[i][j] = __builtin_amdgcn_mfma_f32_16x16x32_bf16(
                        af[i], bfr[j], acc[i][j], 0, 0, 0);
        }
    }

    uint8_t* C8 = (uint8_t*)C;
    const int rq = (ln >> 4) * 4;
    #pragma unroll
    for (int j = 0; j < 4; j++) {
        const int col = n0 + wn * 64 + j * 16 + fr;
        const float bv = bias[col];
        #pragma unroll
        for (int i = 0; i < 4; i++) {
            #pragma unroll
            for (int r = 0; r < 4; r++) {
                const int row = m0 + wm * 64 + i * 16 + rq + r;
                float v = acc[i][j][r] + bv;
                if (relu) v = fmaxf(v, 0.f);
                if (mode == 0) {
                    C[(size_t)row * N + col] = f2bf(v);
                } else {
                    const int bb = (row >= S_) ? 1 : 0;
                    const int loc = row - bb * S_;
                    const int hh = col >> 5, ch = col & 31;
                    const int pk = __builtin_amdgcn_cvt_pk_fp8_f32(v, v, 0, false);
                    C8[((size_t)(bb * 8 + hh) * S_ + loc) * 32 + ch] = (uint8_t)(pk & 0xff);
                }
            }
        }
    }
}

// ---------------------------------------------------------------------------
// Residual + LayerNorm, wave-per-row, vectorized, no LDS/barriers.
// ---------------------------------------------------------------------------
__global__ __launch_bounds__(256) void ln_row(
    const ushort* __restrict__ a16, const ushort* __restrict__ r16,
    const float* __restrict__ g, const float* __restrict__ be,
    float* __restrict__ o32, ushort* __restrict__ o16)
{
    const int wv = threadIdx.x >> 6, ln = threadIdx.x & 63;
    const int row = blockIdx.x * 4 + wv;
    const int col = ln * 4;
    const size_t base = (size_t)row * 256 + col;

    const ushort4 av = *(const ushort4*)(a16 + base);
    const ushort4 rv = *(const ushort4*)(r16 + base);
    float v0 = bf2f(av.x) + bf2f(rv.x);
    float v1 = bf2f(av.y) + bf2f(rv.y);
    float v2 = bf2f(av.z) + bf2f(rv.z);
    float v3 = bf2f(av.w) + bf2f(rv.w);

    float s = v0 + v1 + v2 + v3;
    float s2 = v0 * v0 + v1 * v1 + v2 * v2 + v3 * v3;
    #pragma unroll
    for (int o = 32; o > 0; o >>= 1) {
        s  += __shfl_down(s, o);
        s2 += __shfl_down(s2, o);
    }
    s = __shfl(s, 0);
    s2 = __shfl(s2, 0);
    const float mean = s * (1.f / 256.f);
    const float var = s2 * (1.f / 256.f) - mean * mean;
    const float rstd = rsqrtf(var + EPS_);

    const float4 gv = *(const float4*)(g + col);
    const float4 bv = *(const float4*)(be + col);
    const float o0 = (v0 - mean) * rstd * gv.x + bv.x;
    const float o1 = (v1 - mean) * rstd * gv.y + bv.y;
    const float o2 = (v2 - mean) * rstd * gv.z + bv.z;
    const float o3 = (v3 - mean) * rstd * gv.w + bv.w;

    if (o32) {
        float4 o; o.x = o0; o.y = o1; o.z = o2; o.w = o3;
        *(float4*)(o32 + base) = o;
    } else {
        ushort4 o; o.x = f2bf(o0); o.y = f2bf(o1); o.z = f2bf(o2); o.w = f2bf(o3);
        *(ushort4*)(o16 + base) = o;
    }
}

// ---------------------------------------------------------------------------
// Deformable sampling v8: (b,h)-partitioned blocks for L2-resident gathers.
// ---------------------------------------------------------------------------
__global__ __launch_bounds__(256) void sample8(
    const uint8_t* __restrict__ value, const ushort* __restrict__ offaw,
    const float* __restrict__ refp, ushort* __restrict__ samp)
{
    const int bid = blockIdx.x;
    const int wg = (bid & 7) * 680 + (bid >> 3);
    const int bh = wg / 340;                      // 0..15
    const int qc = wg - bh * 340;                 // q-chunk
    const int b = bh >> 3, h = bh & 7;

    const int tid = threadIdx.x;
    const int g = tid >> 2, cg = tid & 3;
    const int q = b * S_ + qc * 64 + g;           // global row in [0,M)
    const int half = cg >> 1;
    const int gbase = (tid & 63) & ~3;

    const int Wl = 128 >> cg;
    const float fW = (float)Wl;
    const int st = (cg == 0) ? 0 : (cg == 1) ? 16384 : (cg == 2) ? 20480 : 21504;

    const ushort* awq = offaw + (size_t)q * 384 + 256 + h * 16 + cg * 4;
    const uint2 lg = *(const uint2*)awq;
    const float l0 = bf2f((ushort)(lg.x & 0xffff)), l1 = bf2f((ushort)(lg.x >> 16));
    const float l2 = bf2f((ushort)(lg.y & 0xffff)), l3 = bf2f((ushort)(lg.y >> 16));
    float mx = fmaxf(fmaxf(l0, l1), fmaxf(l2, l3));
    mx = fmaxf(mx, __shfl_xor(mx, 1));
    mx = fmaxf(mx, __shfl_xor(mx, 2));
    const float e0 = __expf(l0 - mx), e1 = __expf(l1 - mx);
    const float e2 = __expf(l2 - mx), e3 = __expf(l3 - mx);
    float sm = e0 + e1 + e2 + e3;
    sm += __shfl_xor(sm, 1);
    sm += __shfl_xor(sm, 2);
    const float inv = 1.f / sm;
    const float aj[4] = {e0 * inv, e1 * inv, e2 * inv, e3 * inv};

    const ushort* ofq = offaw + (size_t)q * 384 + h * 32 + cg * 8;
    const uint4 of = *(const uint4*)ofq;
    const uint ou[4] = {of.x, of.y, of.z, of.w};
    const float rx = refp[(size_t)q * 8 + cg * 2];
    const float ry = refp[(size_t)q * 8 + cg * 2 + 1];

    int  rxo[8];
    uint wpk[8];                                  // bf16(wA) | bf16(wB)<<16
    #pragma unroll
    for (int j = 0; j < 4; j++) {
        const float ox = bf2f((ushort)(ou[j] & 0xffff));
        const float oy = bf2f((ushort)(ou[j] >> 16));
        const float x = fmaf(rx, fW, ox) - 0.5f;
        const float y = fmaf(ry, fW, oy) - 0.5f;
        const float fx0 = floorf(x), fy0 = floorf(y);
        const float dx = x - fx0, dy = y - fy0;
        const int x0 = (int)fx0, y0 = (int)fy0;

        const int bx = min(max(x0, 0), Wl - 2);
        const float mwx0 = ((x0 >= 0) & (x0 < Wl)) ? (1.f - dx) : 0.f;
        const float mwx1 = ((x0 + 1 >= 0) & (x0 + 1 < Wl)) ? dx : 0.f;
        const int xc0 = min(max(x0, 0), Wl - 1);
        const int xc1 = min(max(x0 + 1, 0), Wl - 1);
        const float wAx = (xc0 == bx ? mwx0 : 0.f) + (xc1 == bx ? mwx1 : 0.f);
        const float wBx = (xc0 == bx + 1 ? mwx0 : 0.f) + (xc1 == bx + 1 ? mwx1 : 0.f);

        const int yc0 = min(max(y0, 0), Wl - 1);
        const int yc1 = min(max(y0 + 1, 0), Wl - 1);
        const float mwy0 = ((y0 >= 0) & (y0 < Wl)) ? (1.f - dy) : 0.f;
        const float mwy1 = ((y0 + 1 >= 0) & (y0 + 1 < Wl)) ? dy : 0.f;

        const float a = aj[j];
        rxo[2 * j]     = (st + yc0 * Wl + bx) * 32;
        rxo[2 * j + 1] = (st + yc1 * Wl + bx) * 32;
        wpk[2 * j]     = (uint)f2bf(a * wAx * mwy0) | ((uint)f2bf(a * wBx * mwy0) << 16);
        wpk[2 * j + 1] = (uint)f2bf(a * wAx * mwy1) | ((uint)f2bf(a * wBx * mwy1) << 16);
    }

    const uint8_t* vb = value + (size_t)(b * 8 + h) * S_ * 32 + cg * 16;
    f32x2 acc[8];
    #pragma unroll
    for (int k = 0; k < 8; k++) acc[k] = (f32x2){0.f, 0.f};

    #pragma unroll
    for (int ol = 0; ol < 4; ol++) {
        const int srcl = gbase + ol;
        #pragma unroll
        for (int r = 0; r < 8; r++) {
            const int  rix = __shfl(rxo[r], srcl, 64);
            const uint wp  = (uint)__shfl((int)wpk[r], srcl, 64);
            const float wv = bf2f((ushort)(half ? (wp >> 16) : (wp & 0xffffu)));
            const uint4 u = *(const uint4*)(vb + rix);
            const f32x2 w2 = {wv, wv};
            acc[0] += w2 * __builtin_amdgcn_cvt_pk_f32_fp8((int)u.x, false);
            acc[1] += w2 * __builtin_amdgcn_cvt_pk_f32_fp8((int)u.x, true);
            acc[2] += w2 * __builtin_amdgcn_cvt_pk_f32_fp8((int)u.y, false);
            acc[3] += w2 * __builtin_amdgcn_cvt_pk_f32_fp8((int)u.y, true);
            acc[4] += w2 * __builtin_amdgcn_cvt_pk_f32_fp8((int)u.z, false);
            acc[5] += w2 * __builtin_amdgcn_cvt_pk_f32_fp8((int)u.z, true);
            acc[6] += w2 * __builtin_amdgcn_cvt_pk_f32_fp8((int)u.w, false);
            acc[7] += w2 * __builtin_amdgcn_cvt_pk_f32_fp8((int)u.w, true);
        }
    }

    #pragma unroll
    for (int k = 0; k < 8; k++) {
        acc[k].x += __shfl_xor(acc[k].x, 2);
        acc[k].y += __shfl_xor(acc[k].y, 2);
    }

    f32x2 r0, r1, r2, r3;
    if (half == 0) { r0 = acc[0]; r1 = acc[1]; r2 = acc[2]; r3 = acc[3]; }
    else           { r0 = acc[4]; r1 = acc[5]; r2 = acc[6]; r3 = acc[7]; }

    const int ch_start = (cg & 1) * 16 + half * 8;
    uint4 o;
    o.x = (uint)f2bf(r0.x) | ((uint)f2bf(r0.y) << 16);
    o.y = (uint)f2bf(r1.x) | ((uint)f2bf(r1.y) << 16);
    o.z = (uint)f2bf(r2.x) | ((uint)f2bf(r2.y) << 16);
    o.w = (uint)f2bf(r3.x) | ((uint)f2bf(r3.y) << 16);
    *(uint4*)(samp + (size_t)q * 256 + h * 32 + ch_start) = o;
}

// ---------------------------------------------------------------------------
extern "C" void kernel_launch(void* const* d_in, const int* in_sizes, int n_in,
                              void* d_out, int out_size, void* d_ws, size_t ws_size,
                              hipStream_t stream)
{
    const float* src    = (const float*)d_in[0];
    const float* pos    = (const float*)d_in[1];
    const float* refp   = (const float*)d_in[2];
    const float* W_off  = (const float*)d_in[5];
    const float* b_off  = (const float*)d_in[6];
    const float* W_attn = (const float*)d_in[7];
    const float* b_attn = (const float*)d_in[8];
    const float* W_val  = (const float*)d_in[9];
    const float* b_val  = (const float*)d_in[10];
    const float* W_out  = (const float*)d_in[11];
    const float* b_out  = (const float*)d_in[12];
    const float* g1     = (const float*)d_in[13];
    const float* be1    = (const float*)d_in[14];
    const float* W_ff1  = (const float*)d_in[15];
    const float* b_ff1  = (const float*)d_in[16];
    const float* W_ff2  = (const float*)d_in[17];
    const float* b_ff2  = (const float*)d_in[18];
    const float* g2     = (const float*)d_in[19];
    const float* be2    = (const float*)d_in[20];
    float* out = (float*)d_out;

    const size_t szMDh = (size_t)M_ * 256 * 2;      // 22,282,240 B
    const size_t szOAh = (size_t)M_ * 384 * 2;      // 33,423,360 B

    char* ws = (char*)d_ws;
    ushort* WT      = (ushort*)ws;
    ushort* WT_val  = WT;
    ushort* WT_oa   = WT + 65536;
    ushort* WT_out  = WT + 163840;
    ushort* WT_ff1  = WT + 229376;
    ushort* WT_ff2  = WT + 491520;
    float*  bias_oa = (float*)(ws + 1507328);

    const size_t o_src  = 2097152;
    const size_t o_q    = o_src + szMDh;
    const size_t o_val  = o_q   + szMDh;
    const size_t o_oa   = o_val + szMDh;
    const size_t o_x    = o_oa  + szOAh;
    const size_t o_ffn  = o_x   + szMDh;            // total 146.9 MB (proven fit)

    ushort* src_bf  = (ushort*)(ws + o_src);
    ushort* q_bf    = (ushort*)(ws + o_q);
    ushort* val_f8  = (ushort*)(ws + o_val);
    ushort* offaw   = (ushort*)(ws + o_oa);
    ushort* x_bf    = (ushort*)(ws + o_x);
    ushort* ffn_bf  = (ushort*)(ws + o_ffn);
    ushort* samp_bf = q_bf;      // q_bf dead after offaw GEMM
    ushort* attn_bf = val_f8;    // val dead after sampling
    ushort* hbuf    = src_bf;    // src..oa free after ln1 (100.3 MB >= 89.1)

    // 0) converts (src/q) + all weight transposes, one dispatch
    prep_all<<<CVT_BLOCKS + 2947, 256, 0, stream>>>(
        src, pos, src_bf, q_bf,
        W_val, W_off, W_attn, W_out, W_ff1, W_ff2, b_off, b_attn, WT, bias_oa);
    // 1) value = src @ W_val + b_val  (fp8 head-major)
    mgemm<<<2 * (M_ / 128), 256, 0, stream>>>(src_bf, WT_val, b_val, val_f8, M_, 256, 256, 0, 2);
    // 2) offaw = (src+pos) @ [W_off|W_attn] + bias
    mgemm<<<3 * (M_ / 128), 256, 0, stream>>>(q_bf, WT_oa, bias_oa, offaw, M_, 384, 256, 0, 0);
    // 3) sampling ((b,h)-partitioned, L2-resident)
    sample8<<<16 * 340, 256, 0, stream>>>((const uint8_t*)val_f8, offaw, refp, samp_bf);
    // 4) attn_out = samp @ W_out + b_out
    mgemm<<<2 * (M_ / 128), 256, 0, stream>>>(samp_bf, WT_out, b_out, attn_bf, M_, 256, 256, 0, 0);
    // 5) x = LN(src_bf + attn)
    ln_row<<<M_ / 4, 256, 0, stream>>>(attn_bf, src_bf, g1, be1, nullptr, x_bf);
    // 6) FFN1: h = relu(x @ W_ff1 + b_ff1)
    mgemm<<<8 * (M_ / 128), 256, 0, stream>>>(x_bf, WT_ff1, b_ff1, hbuf, M_, DFF_, 256, 1, 0);
    // 7) FFN2: ffn = h @ W_ff2 + b_ff2
    mgemm<<<2 * (M_ / 128), 256, 0, stream>>>(hbuf, WT_ff2, b_ff2, ffn_bf, M_, 256, DFF_, 0, 0);
    // 8) out = LN(x + ffn)
    ln_row<<<M_ / 4, 256, 0, stream>>>(ffn_bf, x_bf, g2, be2, out, nullptr);
}